// Round 5
// baseline (681.305 us; speedup 1.0000x reference)
//
#include <hip/hip_runtime.h>
#include <hip/hip_bf16.h>
#include <math.h>

#define B_G  256
#define NPG  128
#define KNN_ 4
#define CIN  53
#define N1   32768
#define KP1  103
#define N2   26368   // 256*103
#define KP2  83
#define N3   21248   // 256*83
#define O1   128
#define O2   256
#define O3   512
#define EPSB 1e-5f

// ---------------- weight packing: W[2K][O] -> Wp[K][2O] (A-part | C-part) ---
__global__ void pack_w_k(const float* __restrict__ W, float* __restrict__ Wp,
                         int Kd, int O) {
    int i = blockIdx.x * blockDim.x + threadIdx.x;
    int tot = Kd * 2 * O;
    if (i >= tot) return;
    int k = i / (2 * O), c = i % (2 * O);
    Wp[i] = (c < O) ? W[k * O + c] : W[(Kd + k) * O + (c - O)];
}

// ---------------- normalize pool weight vector ----------------------------
__global__ void norm_w_k(const float* __restrict__ pw, float* __restrict__ pwn, int O) {
    __shared__ float red[256];
    float s = 0.f;
    for (int c = threadIdx.x; c < O; c += 256) s += pw[c] * pw[c];
    red[threadIdx.x] = s;
    __syncthreads();
    for (int st = 128; st > 0; st >>= 1) {
        if (threadIdx.x < st) red[threadIdx.x] += red[threadIdx.x + st];
        __syncthreads();
    }
    float inv = 1.0f / sqrtf(red[0]);
    for (int c = threadIdx.x; c < O; c += 256) pwn[c] = pw[c] * inv;
}

// ---------------- KNN (k=4, per-graph, loop excluded) ---------------------
__global__ void knn_k(const float* __restrict__ pos, int* __restrict__ nbr) {
    int g = blockIdx.x;
    int i = threadIdx.x;  // 128 threads
    __shared__ float px[NPG], py[NPG], pz[NPG];
    const float* p = pos + (size_t)g * NPG * 3;
    px[i] = p[i * 3 + 0]; py[i] = p[i * 3 + 1]; pz[i] = p[i * 3 + 2];
    __syncthreads();
    float bd[4] = {1e30f, 1e30f, 1e30f, 1e30f};
    int   bi[4] = {0, 0, 0, 0};
    float xi = px[i], yi = py[i], zi = pz[i];
    for (int j = 0; j < NPG; ++j) {
        if (j == i) continue;
        float dx = xi - px[j], dy = yi - py[j], dz = zi - pz[j];
        float d2 = dx * dx + dy * dy + dz * dz;
        if (d2 < bd[3]) {                // strict <: ties keep lower index (scan asc.)
            int q = 3;
            while (q > 0 && d2 < bd[q - 1]) { bd[q] = bd[q - 1]; bi[q] = bi[q - 1]; --q; }
            bd[q] = d2; bi[q] = j;
        }
    }
    int base = (g * NPG + i) * KNN_;
    #pragma unroll
    for (int kk = 0; kk < KNN_; ++kk) nbr[base + kk] = g * NPG + bi[kk];
}

// ---------------- fp32 tiled GEMM: C[MxN] = A[MxK(lda)] @ B[KxN] ----------
// 128x128 tile, 256 threads, 8x8 acc per thread (2x2 quadrants of 4x4).
// VEC=1 requires Kd%16==0 and 16B-aligned rows (lda%4==0).
template <int VEC>
__global__ __launch_bounds__(256) void gemm128_k(
        const float* __restrict__ A, const float* __restrict__ Bm,
        float* __restrict__ Cm, int M, int N, int Kd, int lda) {
    __shared__ float As[16][128];   // transposed: As[k][row]
    __shared__ float Bs[16][128];
    const int tid = threadIdx.x;
    const int row0 = blockIdx.y * 128, col0 = blockIdx.x * 128;
    const int tx = tid & 15;        // col quad selector
    const int ty = (tid >> 4) & 15; // row quad selector (0..15)
    const int s_arow = tid >> 1, s_ak = (tid & 1) * 8;     // A staging
    const int s_bk = tid >> 4, s_bc = (tid & 15) * 8;      // B staging
    float acc[8][8] = {};
    for (int k0 = 0; k0 < Kd; k0 += 16) {
        if (VEC) {
            const float4* ap = (const float4*)(A + (size_t)(row0 + s_arow) * lda + k0 + s_ak);
            float4 a0 = ap[0], a1 = ap[1];
            As[s_ak + 0][s_arow] = a0.x; As[s_ak + 1][s_arow] = a0.y;
            As[s_ak + 2][s_arow] = a0.z; As[s_ak + 3][s_arow] = a0.w;
            As[s_ak + 4][s_arow] = a1.x; As[s_ak + 5][s_arow] = a1.y;
            As[s_ak + 6][s_arow] = a1.z; As[s_ak + 7][s_arow] = a1.w;
            const float4* bp = (const float4*)(Bm + (size_t)(k0 + s_bk) * N + col0 + s_bc);
            float4 b0 = bp[0], b1 = bp[1];
            *(float4*)&Bs[s_bk][s_bc] = b0;
            *(float4*)&Bs[s_bk][s_bc + 4] = b1;
        } else {
            #pragma unroll
            for (int s = 0; s < 8; ++s) {
                int kk = s_ak + s;
                As[kk][s_arow] = (k0 + kk < Kd)
                    ? A[(size_t)(row0 + s_arow) * lda + k0 + kk] : 0.f;
            }
            #pragma unroll
            for (int s = 0; s < 8; ++s) {
                Bs[s_bk][s_bc + s] = (k0 + s_bk < Kd)
                    ? Bm[(size_t)(k0 + s_bk) * N + col0 + s_bc + s] : 0.f;
            }
        }
        __syncthreads();
        #pragma unroll
        for (int kk = 0; kk < 16; ++kk) {
            float a[8], b[8];
            *(float4*)&a[0] = *(const float4*)&As[kk][ty * 4];
            *(float4*)&a[4] = *(const float4*)&As[kk][64 + ty * 4];
            *(float4*)&b[0] = *(const float4*)&Bs[kk][tx * 4];
            *(float4*)&b[4] = *(const float4*)&Bs[kk][64 + tx * 4];
            #pragma unroll
            for (int i = 0; i < 8; ++i)
                #pragma unroll
                for (int j = 0; j < 8; ++j)
                    acc[i][j] += a[i] * b[j];
        }
        __syncthreads();
    }
    #pragma unroll
    for (int i = 0; i < 8; ++i) {
        int r = row0 + ((i < 4) ? (ty * 4 + i) : (64 + ty * 4 + (i - 4)));
        size_t base = (size_t)r * N + col0;
        *(float4*)&Cm[base + tx * 4]      = *(float4*)&acc[i][0];
        *(float4*)&Cm[base + 64 + tx * 4] = *(float4*)&acc[i][4];
    }
}

// ---------------- EdgeConv aggregation ------------------------------------
// AC[node][2O] = [A | C]; edge pre-act = A_i + bias - C_i + C_j ; h = BN(mean relu)
__global__ void conv_agg_k(const float* __restrict__ AC, const int* __restrict__ edges,
                           const float* __restrict__ bias, const float* __restrict__ g,
                           const float* __restrict__ be, const float* __restrict__ rm,
                           const float* __restrict__ rv, float* __restrict__ out, int O) {
    int node = blockIdx.x;
    int c = threadIdx.x;            // blockDim == O
    int e0 = node * KNN_;
    int j0 = edges[e0 + 0], j1 = edges[e0 + 1], j2 = edges[e0 + 2], j3 = edges[e0 + 3];
    size_t s2O = (size_t)2 * O;
    float Ai = AC[(size_t)node * s2O + c];
    float Ci = AC[(size_t)node * s2O + O + c];
    float base = Ai - Ci + bias[c];
    float acc = 0.f; int cnt = 0;
    if (j0 >= 0) { acc += fmaxf(base + AC[(size_t)j0 * s2O + O + c], 0.f); ++cnt; }
    if (j1 >= 0) { acc += fmaxf(base + AC[(size_t)j1 * s2O + O + c], 0.f); ++cnt; }
    if (j2 >= 0) { acc += fmaxf(base + AC[(size_t)j2 * s2O + O + c], 0.f); ++cnt; }
    if (j3 >= 0) { acc += fmaxf(base + AC[(size_t)j3 * s2O + O + c], 0.f); ++cnt; }
    float h;
    if (cnt > 0) {
        float m = acc / (float)cnt;
        float sc = g[c] / sqrtf(rv[c] + EPSB);
        h = (m - rm[c]) * sc + be[c];
    } else {
        h = 0.f;
    }
    out[(size_t)node * O + c] = h;
}

// ---------------- pooling score: sc[u] = dot(h[u], pwn) -------------------
__global__ void score_k(const float* __restrict__ h, const float* __restrict__ pwn,
                        float* __restrict__ sc, int Nl, int O) {
    int wid = (blockIdx.x * blockDim.x + threadIdx.x) >> 6;
    int lane = threadIdx.x & 63;
    if (wid >= Nl) return;
    float s = 0.f;
    for (int c = lane; c < O; c += 64) s += h[(size_t)wid * O + c] * pwn[c];
    #pragma unroll
    for (int off = 32; off > 0; off >>= 1) s += __shfl_down(s, off);
    if (lane == 0) sc[wid] = s;
}

// ---------------- per-graph top-k selection (1 wave / graph) --------------
__global__ void topk_k(const float* __restrict__ sc, int n_l, int k_keep,
                       float* __restrict__ gate, int* __restrict__ perm,
                       int* __restrict__ o2n) {
    int g = blockIdx.x;
    int lane = threadIdx.x;          // 64 threads
    int t0 = lane, t1 = lane + 64;
    float v0 = (t0 < n_l) ? sc[(size_t)g * n_l + t0] : -INFINITY;
    float v1 = (t1 < n_l) ? sc[(size_t)g * n_l + t1] : -INFINITY;
    float ov0 = v0, ov1 = v1;
    int r0 = -1, r1 = -1;
    for (int r = 0; r < k_keep; ++r) {
        float bv; int bi;
        if (v0 >= v1) { bv = v0; bi = t0; } else { bv = v1; bi = t1; }  // tie -> lower idx
        #pragma unroll
        for (int m = 32; m > 0; m >>= 1) {
            float wv = __shfl_xor(bv, m);
            int   wi = __shfl_xor(bi, m);
            if (wv > bv || (wv == bv && wi < bi)) { bv = wv; bi = wi; }
        }
        if (bi == t0)      { v0 = -INFINITY; r0 = r; }
        else if (bi == t1) { v1 = -INFINITY; r1 = r; }
    }
    if (t0 < n_l) {
        if (r0 >= 0) {
            int d = g * k_keep + r0;
            perm[d] = g * n_l + t0; gate[d] = tanhf(ov0); o2n[g * n_l + t0] = d;
        } else o2n[g * n_l + t0] = -1;
    }
    if (t1 < n_l) {
        if (r1 >= 0) {
            int d = g * k_keep + r1;
            perm[d] = g * n_l + t1; gate[d] = tanhf(ov1); o2n[g * n_l + t1] = d;
        } else o2n[g * n_l + t1] = -1;
    }
}

// ---------------- gather pooled features ----------------------------------
__global__ void gather_k(const float* __restrict__ h, const int* __restrict__ perm,
                         const float* __restrict__ gate, float* __restrict__ xo,
                         int total, int oshift) {
    int i = blockIdx.x * blockDim.x + threadIdx.x;
    if (i >= total) return;
    int d = i >> oshift, c = i & ((1 << oshift) - 1);
    xo[i] = h[((size_t)perm[d] << oshift) + c] * gate[d];
}

// ---------------- edge remapping ------------------------------------------
__global__ void build_e2_k(const int* __restrict__ nbr, const int* __restrict__ perm1,
                           const int* __restrict__ o2n1, int* __restrict__ e2, int total) {
    int i = blockIdx.x * blockDim.x + threadIdx.x;
    if (i >= total) return;
    int u = i >> 2, kk = i & 3;
    e2[i] = o2n1[nbr[perm1[u] * KNN_ + kk]];
}

__global__ void build_e3_k(const int* __restrict__ e2, const int* __restrict__ perm2,
                           const int* __restrict__ o2n2, int* __restrict__ e3, int total) {
    int i = blockIdx.x * blockDim.x + threadIdx.x;
    if (i >= total) return;
    int v = i >> 2, kk = i & 3;
    int s1 = e2[perm2[v] * KNN_ + kk];
    e3[i] = (s1 >= 0) ? o2n2[s1] : -1;
}

// ---------------- global mean pool over k2=83 nodes -----------------------
__global__ void gmp_k(const float* __restrict__ h3, float* __restrict__ gmp) {
    int g = blockIdx.x, c = threadIdx.x;  // 512 threads
    float s = 0.f;
    for (int r = 0; r < KP2; ++r) s += h3[((size_t)(g * KP2 + r)) * O3 + c];
    gmp[(size_t)g * O3 + c] = s / (float)KP2;
}

// ---------------- classifier layer 1: BN(ReLU(X@W + b)) -------------------
__global__ void mlpc_k(const float* __restrict__ X, const float* __restrict__ W,
                       const float* __restrict__ bias, const float* __restrict__ g,
                       const float* __restrict__ be, const float* __restrict__ rm,
                       const float* __restrict__ rv, float* __restrict__ out) {
    int b = blockIdx.x, o = threadIdx.x;  // 512 threads
    __shared__ float xr[512];
    xr[o] = X[(size_t)b * 512 + o];
    __syncthreads();
    float acc = bias[o];
    for (int k = 0; k < 512; ++k) acc += xr[k] * W[(size_t)k * 512 + o];
    acc = fmaxf(acc, 0.f);
    float s = g[o] / sqrtf(rv[o] + EPSB);
    out[(size_t)b * 512 + o] = (acc - rm[o]) * s + be[o];
}

// ---------------- classifier layer 2 + sigmoid ----------------------------
__global__ void final_k(const float* __restrict__ z1, const float* __restrict__ Wc2,
                        const float* __restrict__ bc2, const float* __restrict__ gc2,
                        const float* __restrict__ bec2, const float* __restrict__ rmc2,
                        const float* __restrict__ rvc2, float* __restrict__ out) {
    int b = blockIdx.x * blockDim.x + threadIdx.x;
    if (b >= B_G) return;
    float acc = bc2[0];
    for (int k = 0; k < 512; ++k) acc += z1[(size_t)b * 512 + k] * Wc2[k];
    acc = fmaxf(acc, 0.f);
    float s = gc2[0] / sqrtf(rvc2[0] + EPSB);
    float z = (acc - rmc2[0]) * s + bec2[0];
    out[b] = 1.f / (1.f + expf(-z));
}

// ==========================================================================
extern "C" void kernel_launch(void* const* d_in, const int* in_sizes, int n_in,
                              void* d_out, int out_size, void* d_ws, size_t ws_size,
                              hipStream_t stream) {
    const float* x    = (const float*)d_in[0];
    const float* pos  = (const float*)d_in[1];
    const float* W1   = (const float*)d_in[2];
    const float* b1   = (const float*)d_in[3];
    const float* g1   = (const float*)d_in[4];
    const float* be1  = (const float*)d_in[5];
    const float* rm1  = (const float*)d_in[6];
    const float* rv1  = (const float*)d_in[7];
    const float* pw1  = (const float*)d_in[8];
    const float* W2   = (const float*)d_in[9];
    const float* b2   = (const float*)d_in[10];
    const float* g2   = (const float*)d_in[11];
    const float* be2  = (const float*)d_in[12];
    const float* rm2  = (const float*)d_in[13];
    const float* rv2  = (const float*)d_in[14];
    const float* pw2  = (const float*)d_in[15];
    const float* W3   = (const float*)d_in[16];
    const float* b3   = (const float*)d_in[17];
    const float* g3   = (const float*)d_in[18];
    const float* be3  = (const float*)d_in[19];
    const float* rm3  = (const float*)d_in[20];
    const float* rv3  = (const float*)d_in[21];
    const float* Wc1  = (const float*)d_in[22];
    const float* bc1  = (const float*)d_in[23];
    const float* gc1  = (const float*)d_in[24];
    const float* bec1 = (const float*)d_in[25];
    const float* rmc1 = (const float*)d_in[26];
    const float* rvc1 = (const float*)d_in[27];
    const float* Wc2  = (const float*)d_in[28];
    const float* bc2  = (const float*)d_in[29];
    const float* gc2  = (const float*)d_in[30];
    const float* bec2 = (const float*)d_in[31];
    const float* rmc2 = (const float*)d_in[32];
    const float* rvc2 = (const float*)d_in[33];
    float* out = (float*)d_out;

    // ---- workspace layout (two aliased big slabs S1/S2) ----
    char* ws = (char*)d_ws;
    size_t off = 0;
    auto take = [&](size_t bytes) { size_t o = off; off = (off + bytes + 255) & ~(size_t)255; return o; };
    size_t o_nbr   = take((size_t)N1 * KNN_ * 4);
    size_t o_perm1 = take((size_t)N2 * 4);
    size_t o_o2n1  = take((size_t)N1 * 4);
    size_t o_perm2 = take((size_t)N3 * 4);
    size_t o_o2n2  = take((size_t)N2 * 4);
    size_t o_e2    = take((size_t)N2 * KNN_ * 4);
    size_t o_e3    = take((size_t)N3 * KNN_ * 4);
    size_t o_pwn1  = take((size_t)O1 * 4);
    size_t o_pwn2  = take((size_t)O2 * 4);
    size_t o_sc1   = take((size_t)N1 * 4);
    size_t o_sc2   = take((size_t)N2 * 4);
    size_t o_gate1 = take((size_t)N2 * 4);
    size_t o_gate2 = take((size_t)N3 * 4);
    size_t o_Wp1   = take((size_t)CIN * 2 * O1 * 4);
    size_t o_Wp2   = take((size_t)O1 * 2 * O2 * 4);
    size_t o_Wp3   = take((size_t)O2 * 2 * O3 * 4);
    size_t o_gmp   = take((size_t)B_G * O3 * 4);
    size_t o_z1    = take((size_t)B_G * O3 * 4);
    size_t o_S1    = take((size_t)N3 * 2 * O3 * 4);   // max: AC3 = 21248*1024
    size_t o_S2    = take((size_t)N2 * 2 * O2 * 4);   // max: AC2 = 26368*512

    int*   nbr   = (int*)(ws + o_nbr);
    int*   perm1 = (int*)(ws + o_perm1);
    int*   o2n1  = (int*)(ws + o_o2n1);
    int*   perm2 = (int*)(ws + o_perm2);
    int*   o2n2  = (int*)(ws + o_o2n2);
    int*   e2    = (int*)(ws + o_e2);
    int*   e3    = (int*)(ws + o_e3);
    float* pwn1  = (float*)(ws + o_pwn1);
    float* pwn2  = (float*)(ws + o_pwn2);
    float* sc1   = (float*)(ws + o_sc1);
    float* sc2   = (float*)(ws + o_sc2);
    float* gate1 = (float*)(ws + o_gate1);
    float* gate2 = (float*)(ws + o_gate2);
    float* Wp1   = (float*)(ws + o_Wp1);
    float* Wp2   = (float*)(ws + o_Wp2);
    float* Wp3   = (float*)(ws + o_Wp3);
    float* gmpb  = (float*)(ws + o_gmp);
    float* z1b   = (float*)(ws + o_z1);
    float* S1    = (float*)(ws + o_S1);
    float* S2    = (float*)(ws + o_S2);

    float* AC1 = S1;  float* h1  = S2;
    float* x1p = S1;  float* AC2 = S2;
    float* h2  = S1;  float* x2p = S2;
    float* AC3 = S1;  float* h3  = S2;

    // ---- prep: pack weights, normalize pool vectors, knn ----
    pack_w_k<<<(CIN * 2 * O1 + 255) / 256, 256, 0, stream>>>(W1, Wp1, CIN, O1);
    pack_w_k<<<(O1 * 2 * O2 + 255) / 256, 256, 0, stream>>>(W2, Wp2, O1, O2);
    pack_w_k<<<(O2 * 2 * O3 + 255) / 256, 256, 0, stream>>>(W3, Wp3, O2, O3);
    norm_w_k<<<1, 256, 0, stream>>>(pw1, pwn1, O1);
    norm_w_k<<<1, 256, 0, stream>>>(pw2, pwn2, O2);
    knn_k<<<B_G, NPG, 0, stream>>>(pos, nbr);

    // ---- level 1 ----  (K=53: scalar-guarded staging path)
    gemm128_k<0><<<dim3(2 * O1 / 128, N1 / 128), 256, 0, stream>>>(
        x, Wp1, AC1, N1, 2 * O1, CIN, CIN);
    conv_agg_k<<<N1, O1, 0, stream>>>(AC1, nbr, b1, g1, be1, rm1, rv1, h1, O1);
    score_k<<<(N1 + 3) / 4, 256, 0, stream>>>(h1, pwn1, sc1, N1, O1);
    topk_k<<<B_G, 64, 0, stream>>>(sc1, NPG, KP1, gate1, perm1, o2n1);
    gather_k<<<(N2 * O1 + 255) / 256, 256, 0, stream>>>(h1, perm1, gate1, x1p, N2 * O1, 7);
    build_e2_k<<<(N2 * KNN_ + 255) / 256, 256, 0, stream>>>(nbr, perm1, o2n1, e2, N2 * KNN_);

    // ---- level 2 ----  (K=128: vectorized staging)
    gemm128_k<1><<<dim3(2 * O2 / 128, N2 / 128), 256, 0, stream>>>(
        x1p, Wp2, AC2, N2, 2 * O2, O1, O1);
    conv_agg_k<<<N2, O2, 0, stream>>>(AC2, e2, b2, g2, be2, rm2, rv2, h2, O2);
    score_k<<<(N2 + 3) / 4, 256, 0, stream>>>(h2, pwn2, sc2, N2, O2);
    topk_k<<<B_G, 64, 0, stream>>>(sc2, KP1, KP2, gate2, perm2, o2n2);
    gather_k<<<(N3 * O2 + 255) / 256, 256, 0, stream>>>(h2, perm2, gate2, x2p, N3 * O2, 8);
    build_e3_k<<<(N3 * KNN_ + 255) / 256, 256, 0, stream>>>(e2, perm2, o2n2, e3, N3 * KNN_);

    // ---- level 3 ----  (K=256: vectorized staging)
    gemm128_k<1><<<dim3(2 * O3 / 128, N3 / 128), 256, 0, stream>>>(
        x2p, Wp3, AC3, N3, 2 * O3, O2, O2);
    conv_agg_k<<<N3, O3, 0, stream>>>(AC3, e3, b3, g3, be3, rm3, rv3, h3, O3);

    // ---- readout ----
    gmp_k<<<B_G, O3, 0, stream>>>(h3, gmpb);
    mlpc_k<<<B_G, 512, 0, stream>>>(gmpb, Wc1, bc1, gc1, bec1, rmc1, rvc1, z1b);
    final_k<<<1, 256, 0, stream>>>(z1b, Wc2, bc2, gc2, bec2, rmc2, rvc2, out);
}

// Round 6
// 602.005 us; speedup vs baseline: 1.1317x; 1.1317x over previous
//
#include <hip/hip_runtime.h>
#include <hip/hip_bf16.h>
#include <math.h>

#define B_G  256
#define NPG  128
#define KNN_ 4
#define CIN  53
#define N1   32768
#define KP1  103
#define N2   26368   // 256*103
#define KP2  83
#define N3   21248   // 256*83 = 166*128
#define O1   128
#define O2   256
#define O3   512
#define EPSB 1e-5f

typedef __attribute__((ext_vector_type(8))) short bf16x8;
typedef __attribute__((ext_vector_type(4))) float f32x4;

__device__ inline ushort f2bf(float f) {          // RNE float->bf16
    unsigned u = __builtin_bit_cast(unsigned, f);
    u += 0x7fff + ((u >> 16) & 1);
    return (ushort)(u >> 16);
}
__device__ inline float bf2f(ushort h) {
    unsigned u = ((unsigned)h) << 16;
    return __builtin_bit_cast(float, u);
}

// ---------------- weight packing: W[2K][O] -> Wp[K][2O] (A-part | C-part) ---
__global__ void pack_w_k(const float* __restrict__ W, float* __restrict__ Wp,
                         int Kd, int O) {
    int i = blockIdx.x * blockDim.x + threadIdx.x;
    int tot = Kd * 2 * O;
    if (i >= tot) return;
    int k = i / (2 * O), c = i % (2 * O);
    Wp[i] = (c < O) ? W[k * O + c] : W[(Kd + k) * O + (c - O)];
}

// ---- W3 -> transposed packed bf16 hi/lo: BT[n][k], n in [0,1024), k in [0,256)
__global__ void pack_w3t_k(const float* __restrict__ W3,
                           ushort* __restrict__ BhT, ushort* __restrict__ BlT) {
    int i = blockIdx.x * blockDim.x + threadIdx.x;   // 1024*256
    if (i >= 1024 * 256) return;
    int n = i >> 8, k = i & 255;
    float w = (n < 512) ? W3[(size_t)k * 512 + n] : W3[(size_t)(256 + k) * 512 + (n - 512)];
    ushort h = f2bf(w);
    BhT[i] = h;
    BlT[i] = f2bf(w - bf2f(h));
}

// ---------------- normalize pool weight vector ----------------------------
__global__ void norm_w_k(const float* __restrict__ pw, float* __restrict__ pwn, int O) {
    __shared__ float red[256];
    float s = 0.f;
    for (int c = threadIdx.x; c < O; c += 256) s += pw[c] * pw[c];
    red[threadIdx.x] = s;
    __syncthreads();
    for (int st = 128; st > 0; st >>= 1) {
        if (threadIdx.x < st) red[threadIdx.x] += red[threadIdx.x + st];
        __syncthreads();
    }
    float inv = 1.0f / sqrtf(red[0]);
    for (int c = threadIdx.x; c < O; c += 256) pwn[c] = pw[c] * inv;
}

// ---------------- KNN (k=4, per-graph, loop excluded) ---------------------
__global__ void knn_k(const float* __restrict__ pos, int* __restrict__ nbr) {
    int g = blockIdx.x;
    int i = threadIdx.x;  // 128 threads
    __shared__ float px[NPG], py[NPG], pz[NPG];
    const float* p = pos + (size_t)g * NPG * 3;
    px[i] = p[i * 3 + 0]; py[i] = p[i * 3 + 1]; pz[i] = p[i * 3 + 2];
    __syncthreads();
    float bd[4] = {1e30f, 1e30f, 1e30f, 1e30f};
    int   bi[4] = {0, 0, 0, 0};
    float xi = px[i], yi = py[i], zi = pz[i];
    for (int j = 0; j < NPG; ++j) {
        if (j == i) continue;
        float dx = xi - px[j], dy = yi - py[j], dz = zi - pz[j];
        float d2 = dx * dx + dy * dy + dz * dz;
        if (d2 < bd[3]) {
            int q = 3;
            while (q > 0 && d2 < bd[q - 1]) { bd[q] = bd[q - 1]; bi[q] = bi[q - 1]; --q; }
            bd[q] = d2; bi[q] = j;
        }
    }
    int base = (g * NPG + i) * KNN_;
    #pragma unroll
    for (int kk = 0; kk < KNN_; ++kk) nbr[base + kk] = g * NPG + bi[kk];
}

// ---------------- fp32 tiled GEMM (levels 1,2) ----------------------------
template <int VEC>
__global__ __launch_bounds__(256) void gemm128_k(
        const float* __restrict__ A, const float* __restrict__ Bm,
        float* __restrict__ Cm, int M, int N, int Kd, int lda) {
    __shared__ float As[16][128];   // transposed: As[k][row]
    __shared__ float Bs[16][128];
    const int tid = threadIdx.x;
    const int row0 = blockIdx.y * 128, col0 = blockIdx.x * 128;
    const int tx = tid & 15;
    const int ty = (tid >> 4) & 15;
    const int s_arow = tid >> 1, s_ak = (tid & 1) * 8;
    const int s_bk = tid >> 4, s_bc = (tid & 15) * 8;
    float acc[8][8] = {};
    for (int k0 = 0; k0 < Kd; k0 += 16) {
        if (VEC) {
            const float4* ap = (const float4*)(A + (size_t)(row0 + s_arow) * lda + k0 + s_ak);
            float4 a0 = ap[0], a1 = ap[1];
            As[s_ak + 0][s_arow] = a0.x; As[s_ak + 1][s_arow] = a0.y;
            As[s_ak + 2][s_arow] = a0.z; As[s_ak + 3][s_arow] = a0.w;
            As[s_ak + 4][s_arow] = a1.x; As[s_ak + 5][s_arow] = a1.y;
            As[s_ak + 6][s_arow] = a1.z; As[s_ak + 7][s_arow] = a1.w;
            const float4* bp = (const float4*)(Bm + (size_t)(k0 + s_bk) * N + col0 + s_bc);
            float4 b0 = bp[0], b1 = bp[1];
            *(float4*)&Bs[s_bk][s_bc] = b0;
            *(float4*)&Bs[s_bk][s_bc + 4] = b1;
        } else {
            #pragma unroll
            for (int s = 0; s < 8; ++s) {
                int kk = s_ak + s;
                As[kk][s_arow] = (k0 + kk < Kd)
                    ? A[(size_t)(row0 + s_arow) * lda + k0 + kk] : 0.f;
            }
            #pragma unroll
            for (int s = 0; s < 8; ++s) {
                Bs[s_bk][s_bc + s] = (k0 + s_bk < Kd)
                    ? Bm[(size_t)(k0 + s_bk) * N + col0 + s_bc + s] : 0.f;
            }
        }
        __syncthreads();
        #pragma unroll
        for (int kk = 0; kk < 16; ++kk) {
            float a[8], b[8];
            *(float4*)&a[0] = *(const float4*)&As[kk][ty * 4];
            *(float4*)&a[4] = *(const float4*)&As[kk][64 + ty * 4];
            *(float4*)&b[0] = *(const float4*)&Bs[kk][tx * 4];
            *(float4*)&b[4] = *(const float4*)&Bs[kk][64 + tx * 4];
            #pragma unroll
            for (int i = 0; i < 8; ++i)
                #pragma unroll
                for (int j = 0; j < 8; ++j)
                    acc[i][j] += a[i] * b[j];
        }
        __syncthreads();
    }
    #pragma unroll
    for (int i = 0; i < 8; ++i) {
        int r = row0 + ((i < 4) ? (ty * 4 + i) : (64 + ty * 4 + (i - 4)));
        size_t base = (size_t)r * N + col0;
        *(float4*)&Cm[base + tx * 4]      = *(float4*)&acc[i][0];
        *(float4*)&Cm[base + 64 + tx * 4] = *(float4*)&acc[i][4];
    }
}

// ---------------- split-bf16 MFMA GEMM (level 3) --------------------------
// C[N3][1024] = A[N3][256] @ B[256][1024];  A given as bf16 hi/lo planes,
// B given transposed bf16 hi/lo BT[n][k].  C ~= Ah*Bh + Ah*Bl + Al*Bh.
#define LDK 40   // 32 k + 8 pad (bf16 elems) -> 80B row stride
__global__ __launch_bounds__(256) void gemm3_mfma_k(
        const ushort* __restrict__ Ah, const ushort* __restrict__ Al,
        const ushort* __restrict__ BhT, const ushort* __restrict__ BlT,
        float* __restrict__ Cm) {
    __shared__ ushort sAh[128][LDK], sAl[128][LDK], sBh[128][LDK], sBl[128][LDK];
    const int tid = threadIdx.x;
    const int row0 = blockIdx.y * 128, col0 = blockIdx.x * 128;
    const int w = tid >> 6, lane = tid & 63;
    const int wr = (w >> 1) * 64, wc = (w & 1) * 64;   // wave's 64x64 sub-tile
    const int fr = lane & 15, fk = (lane >> 4) * 8;    // fragment row/col, k-offset
    const int s_r = tid >> 2, s_c = (tid & 3) * 8;     // staging: 16B per thread per half-tile
    f32x4 acc[4][4] = {};
    for (int k0 = 0; k0 < 256; k0 += 32) {
        // stage A hi/lo (rows row0+s_r, +64) and B hi/lo (cols col0+s_r, +64)
        {
            size_t ga0 = (size_t)(row0 + s_r) * 256 + k0 + s_c;
            size_t ga1 = (size_t)(row0 + 64 + s_r) * 256 + k0 + s_c;
            *(uint4*)&sAh[s_r][s_c]      = *(const uint4*)&Ah[ga0];
            *(uint4*)&sAh[64 + s_r][s_c] = *(const uint4*)&Ah[ga1];
            *(uint4*)&sAl[s_r][s_c]      = *(const uint4*)&Al[ga0];
            *(uint4*)&sAl[64 + s_r][s_c] = *(const uint4*)&Al[ga1];
            size_t gb0 = (size_t)(col0 + s_r) * 256 + k0 + s_c;
            size_t gb1 = (size_t)(col0 + 64 + s_r) * 256 + k0 + s_c;
            *(uint4*)&sBh[s_r][s_c]      = *(const uint4*)&BhT[gb0];
            *(uint4*)&sBh[64 + s_r][s_c] = *(const uint4*)&BhT[gb1];
            *(uint4*)&sBl[s_r][s_c]      = *(const uint4*)&BlT[gb0];
            *(uint4*)&sBl[64 + s_r][s_c] = *(const uint4*)&BlT[gb1];
        }
        __syncthreads();
        bf16x8 fa_h[4], fa_l[4], fb_h[4], fb_l[4];
        #pragma unroll
        for (int mi = 0; mi < 4; ++mi) {
            fa_h[mi] = *(const bf16x8*)&sAh[wr + mi * 16 + fr][fk];
            fa_l[mi] = *(const bf16x8*)&sAl[wr + mi * 16 + fr][fk];
        }
        #pragma unroll
        for (int ni = 0; ni < 4; ++ni) {
            fb_h[ni] = *(const bf16x8*)&sBh[wc + ni * 16 + fr][fk];
            fb_l[ni] = *(const bf16x8*)&sBl[wc + ni * 16 + fr][fk];
        }
        #pragma unroll
        for (int mi = 0; mi < 4; ++mi)
            #pragma unroll
            for (int ni = 0; ni < 4; ++ni) {
                acc[mi][ni] = __builtin_amdgcn_mfma_f32_16x16x32_bf16(
                    fa_h[mi], fb_h[ni], acc[mi][ni], 0, 0, 0);
                acc[mi][ni] = __builtin_amdgcn_mfma_f32_16x16x32_bf16(
                    fa_h[mi], fb_l[ni], acc[mi][ni], 0, 0, 0);
                acc[mi][ni] = __builtin_amdgcn_mfma_f32_16x16x32_bf16(
                    fa_l[mi], fb_h[ni], acc[mi][ni], 0, 0, 0);
            }
        __syncthreads();
    }
    // C/D layout: col = lane&15, row = (lane>>4)*4 + reg   [m89-verified]
    const int crow = (lane >> 4) * 4, ccol = lane & 15;
    #pragma unroll
    for (int mi = 0; mi < 4; ++mi)
        #pragma unroll
        for (int ni = 0; ni < 4; ++ni) {
            size_t base = (size_t)(row0 + wr + mi * 16 + crow) * 1024
                          + col0 + wc + ni * 16 + ccol;
            #pragma unroll
            for (int r = 0; r < 4; ++r)
                Cm[base + (size_t)r * 1024] = acc[mi][ni][r];
        }
}

// ---------------- EdgeConv aggregation ------------------------------------
__global__ void conv_agg_k(const float* __restrict__ AC, const int* __restrict__ edges,
                           const float* __restrict__ bias, const float* __restrict__ g,
                           const float* __restrict__ be, const float* __restrict__ rm,
                           const float* __restrict__ rv, float* __restrict__ out, int O) {
    int node = blockIdx.x;
    int c = threadIdx.x;            // blockDim == O
    int e0 = node * KNN_;
    int j0 = edges[e0 + 0], j1 = edges[e0 + 1], j2 = edges[e0 + 2], j3 = edges[e0 + 3];
    size_t s2O = (size_t)2 * O;
    float Ai = AC[(size_t)node * s2O + c];
    float Ci = AC[(size_t)node * s2O + O + c];
    float base = Ai - Ci + bias[c];
    float acc = 0.f; int cnt = 0;
    if (j0 >= 0) { acc += fmaxf(base + AC[(size_t)j0 * s2O + O + c], 0.f); ++cnt; }
    if (j1 >= 0) { acc += fmaxf(base + AC[(size_t)j1 * s2O + O + c], 0.f); ++cnt; }
    if (j2 >= 0) { acc += fmaxf(base + AC[(size_t)j2 * s2O + O + c], 0.f); ++cnt; }
    if (j3 >= 0) { acc += fmaxf(base + AC[(size_t)j3 * s2O + O + c], 0.f); ++cnt; }
    float h;
    if (cnt > 0) {
        float m = acc / (float)cnt;
        float sc = g[c] / sqrtf(rv[c] + EPSB);
        h = (m - rm[c]) * sc + be[c];
    } else {
        h = 0.f;
    }
    out[(size_t)node * O + c] = h;
}

// ---------------- pooling score -------------------------------------------
__global__ void score_k(const float* __restrict__ h, const float* __restrict__ pwn,
                        float* __restrict__ sc, int Nl, int O) {
    int wid = (blockIdx.x * blockDim.x + threadIdx.x) >> 6;
    int lane = threadIdx.x & 63;
    if (wid >= Nl) return;
    float s = 0.f;
    for (int c = lane; c < O; c += 64) s += h[(size_t)wid * O + c] * pwn[c];
    #pragma unroll
    for (int off = 32; off > 0; off >>= 1) s += __shfl_down(s, off);
    if (lane == 0) sc[wid] = s;
}

// ---------------- per-graph top-k selection -------------------------------
__global__ void topk_k(const float* __restrict__ sc, int n_l, int k_keep,
                       float* __restrict__ gate, int* __restrict__ perm,
                       int* __restrict__ o2n) {
    int g = blockIdx.x;
    int lane = threadIdx.x;          // 64 threads
    int t0 = lane, t1 = lane + 64;
    float v0 = (t0 < n_l) ? sc[(size_t)g * n_l + t0] : -INFINITY;
    float v1 = (t1 < n_l) ? sc[(size_t)g * n_l + t1] : -INFINITY;
    float ov0 = v0, ov1 = v1;
    int r0 = -1, r1 = -1;
    for (int r = 0; r < k_keep; ++r) {
        float bv; int bi;
        if (v0 >= v1) { bv = v0; bi = t0; } else { bv = v1; bi = t1; }
        #pragma unroll
        for (int m = 32; m > 0; m >>= 1) {
            float wv = __shfl_xor(bv, m);
            int   wi = __shfl_xor(bi, m);
            if (wv > bv || (wv == bv && wi < bi)) { bv = wv; bi = wi; }
        }
        if (bi == t0)      { v0 = -INFINITY; r0 = r; }
        else if (bi == t1) { v1 = -INFINITY; r1 = r; }
    }
    if (t0 < n_l) {
        if (r0 >= 0) {
            int d = g * k_keep + r0;
            perm[d] = g * n_l + t0; gate[d] = tanhf(ov0); o2n[g * n_l + t0] = d;
        } else o2n[g * n_l + t0] = -1;
    }
    if (t1 < n_l) {
        if (r1 >= 0) {
            int d = g * k_keep + r1;
            perm[d] = g * n_l + t1; gate[d] = tanhf(ov1); o2n[g * n_l + t1] = d;
        } else o2n[g * n_l + t1] = -1;
    }
}

// ---------------- gather pooled features (fp32, level 1) ------------------
__global__ void gather_k(const float* __restrict__ h, const int* __restrict__ perm,
                         const float* __restrict__ gate, float* __restrict__ xo,
                         int total, int oshift) {
    int i = blockIdx.x * blockDim.x + threadIdx.x;
    if (i >= total) return;
    int d = i >> oshift, c = i & ((1 << oshift) - 1);
    xo[i] = h[((size_t)perm[d] << oshift) + c] * gate[d];
}

// ---------------- gather pooled features -> bf16 hi/lo (level 2) ----------
__global__ void gather_bf_k(const float* __restrict__ h, const int* __restrict__ perm,
                            const float* __restrict__ gate,
                            ushort* __restrict__ Ah, ushort* __restrict__ Al, int total) {
    int i = blockIdx.x * blockDim.x + threadIdx.x;
    if (i >= total) return;
    int d = i >> 8, c = i & 255;            // O2 == 256
    float v = h[((size_t)perm[d] << 8) + c] * gate[d];
    ushort hh = f2bf(v);
    Ah[i] = hh;
    Al[i] = f2bf(v - bf2f(hh));
}

// ---------------- edge remapping ------------------------------------------
__global__ void build_e2_k(const int* __restrict__ nbr, const int* __restrict__ perm1,
                           const int* __restrict__ o2n1, int* __restrict__ e2, int total) {
    int i = blockIdx.x * blockDim.x + threadIdx.x;
    if (i >= total) return;
    int u = i >> 2, kk = i & 3;
    e2[i] = o2n1[nbr[perm1[u] * KNN_ + kk]];
}

__global__ void build_e3_k(const int* __restrict__ e2, const int* __restrict__ perm2,
                           const int* __restrict__ o2n2, int* __restrict__ e3, int total) {
    int i = blockIdx.x * blockDim.x + threadIdx.x;
    if (i >= total) return;
    int v = i >> 2, kk = i & 3;
    int s1 = e2[perm2[v] * KNN_ + kk];
    e3[i] = (s1 >= 0) ? o2n2[s1] : -1;
}

// ---------------- global mean pool ----------------------------------------
__global__ void gmp_k(const float* __restrict__ h3, float* __restrict__ gmp) {
    int g = blockIdx.x, c = threadIdx.x;  // 512 threads
    float s = 0.f;
    for (int r = 0; r < KP2; ++r) s += h3[((size_t)(g * KP2 + r)) * O3 + c];
    gmp[(size_t)g * O3 + c] = s / (float)KP2;
}

// ---------------- classifier layer 1 --------------------------------------
__global__ void mlpc_k(const float* __restrict__ X, const float* __restrict__ W,
                       const float* __restrict__ bias, const float* __restrict__ g,
                       const float* __restrict__ be, const float* __restrict__ rm,
                       const float* __restrict__ rv, float* __restrict__ out) {
    int b = blockIdx.x, o = threadIdx.x;  // 512 threads
    __shared__ float xr[512];
    xr[o] = X[(size_t)b * 512 + o];
    __syncthreads();
    float acc = bias[o];
    for (int k = 0; k < 512; ++k) acc += xr[k] * W[(size_t)k * 512 + o];
    acc = fmaxf(acc, 0.f);
    float s = g[o] / sqrtf(rv[o] + EPSB);
    out[(size_t)b * 512 + o] = (acc - rm[o]) * s + be[o];
}

// ---------------- classifier layer 2 + sigmoid ----------------------------
__global__ void final_k(const float* __restrict__ z1, const float* __restrict__ Wc2,
                        const float* __restrict__ bc2, const float* __restrict__ gc2,
                        const float* __restrict__ bec2, const float* __restrict__ rmc2,
                        const float* __restrict__ rvc2, float* __restrict__ out) {
    int b = blockIdx.x * blockDim.x + threadIdx.x;
    if (b >= B_G) return;
    float acc = bc2[0];
    for (int k = 0; k < 512; ++k) acc += z1[(size_t)b * 512 + k] * Wc2[k];
    acc = fmaxf(acc, 0.f);
    float s = gc2[0] / sqrtf(rvc2[0] + EPSB);
    float z = (acc - rmc2[0]) * s + bec2[0];
    out[b] = 1.f / (1.f + expf(-z));
}

// ==========================================================================
extern "C" void kernel_launch(void* const* d_in, const int* in_sizes, int n_in,
                              void* d_out, int out_size, void* d_ws, size_t ws_size,
                              hipStream_t stream) {
    const float* x    = (const float*)d_in[0];
    const float* pos  = (const float*)d_in[1];
    const float* W1   = (const float*)d_in[2];
    const float* b1   = (const float*)d_in[3];
    const float* g1   = (const float*)d_in[4];
    const float* be1  = (const float*)d_in[5];
    const float* rm1  = (const float*)d_in[6];
    const float* rv1  = (const float*)d_in[7];
    const float* pw1  = (const float*)d_in[8];
    const float* W2   = (const float*)d_in[9];
    const float* b2   = (const float*)d_in[10];
    const float* g2   = (const float*)d_in[11];
    const float* be2  = (const float*)d_in[12];
    const float* rm2  = (const float*)d_in[13];
    const float* rv2  = (const float*)d_in[14];
    const float* pw2  = (const float*)d_in[15];
    const float* W3   = (const float*)d_in[16];
    const float* b3   = (const float*)d_in[17];
    const float* g3   = (const float*)d_in[18];
    const float* be3  = (const float*)d_in[19];
    const float* rm3  = (const float*)d_in[20];
    const float* rv3  = (const float*)d_in[21];
    const float* Wc1  = (const float*)d_in[22];
    const float* bc1  = (const float*)d_in[23];
    const float* gc1  = (const float*)d_in[24];
    const float* bec1 = (const float*)d_in[25];
    const float* rmc1 = (const float*)d_in[26];
    const float* rvc1 = (const float*)d_in[27];
    const float* Wc2  = (const float*)d_in[28];
    const float* bc2  = (const float*)d_in[29];
    const float* gc2  = (const float*)d_in[30];
    const float* bec2 = (const float*)d_in[31];
    const float* rmc2 = (const float*)d_in[32];
    const float* rvc2 = (const float*)d_in[33];
    float* out = (float*)d_out;

    // ---- workspace layout ----
    char* ws = (char*)d_ws;
    size_t off = 0;
    auto take = [&](size_t bytes) { size_t o = off; off = (off + bytes + 255) & ~(size_t)255; return o; };
    size_t o_nbr   = take((size_t)N1 * KNN_ * 4);
    size_t o_perm1 = take((size_t)N2 * 4);
    size_t o_o2n1  = take((size_t)N1 * 4);
    size_t o_perm2 = take((size_t)N3 * 4);
    size_t o_o2n2  = take((size_t)N2 * 4);
    size_t o_e2    = take((size_t)N2 * KNN_ * 4);
    size_t o_e3    = take((size_t)N3 * KNN_ * 4);
    size_t o_pwn1  = take((size_t)O1 * 4);
    size_t o_pwn2  = take((size_t)O2 * 4);
    size_t o_sc1   = take((size_t)N1 * 4);
    size_t o_sc2   = take((size_t)N2 * 4);
    size_t o_gate1 = take((size_t)N2 * 4);
    size_t o_gate2 = take((size_t)N3 * 4);
    size_t o_Wp1   = take((size_t)CIN * 2 * O1 * 4);
    size_t o_Wp2   = take((size_t)O1 * 2 * O2 * 4);
    size_t o_Bh3   = take((size_t)1024 * 256 * 2);   // W3 bf16 hi (transposed)
    size_t o_Bl3   = take((size_t)1024 * 256 * 2);   // W3 bf16 lo
    size_t o_gmp   = take((size_t)B_G * O3 * 4);
    size_t o_z1    = take((size_t)B_G * O3 * 4);
    size_t o_S1    = take((size_t)N3 * 2 * O3 * 4);   // max: AC3 = 21248*1024 f32
    size_t o_S2    = take((size_t)N2 * 2 * O2 * 4);   // max: AC2 = 26368*512 f32

    int*   nbr   = (int*)(ws + o_nbr);
    int*   perm1 = (int*)(ws + o_perm1);
    int*   o2n1  = (int*)(ws + o_o2n1);
    int*   perm2 = (int*)(ws + o_perm2);
    int*   o2n2  = (int*)(ws + o_o2n2);
    int*   e2    = (int*)(ws + o_e2);
    int*   e3    = (int*)(ws + o_e3);
    float* pwn1  = (float*)(ws + o_pwn1);
    float* pwn2  = (float*)(ws + o_pwn2);
    float* sc1   = (float*)(ws + o_sc1);
    float* sc2   = (float*)(ws + o_sc2);
    float* gate1 = (float*)(ws + o_gate1);
    float* gate2 = (float*)(ws + o_gate2);
    float* Wp1   = (float*)(ws + o_Wp1);
    float* Wp2   = (float*)(ws + o_Wp2);
    ushort* Bh3  = (ushort*)(ws + o_Bh3);
    ushort* Bl3  = (ushort*)(ws + o_Bl3);
    float* gmpb  = (float*)(ws + o_gmp);
    float* z1b   = (float*)(ws + o_z1);
    float* S1    = (float*)(ws + o_S1);
    float* S2    = (float*)(ws + o_S2);

    float* AC1 = S1;  float* h1  = S2;
    float* x1p = S1;  float* AC2 = S2;
    float* h2  = S1;
    ushort* x2h = (ushort*)S2;                       // 21248*256 bf16 hi
    ushort* x2l = (ushort*)(S2 + (size_t)N3 * 256);  // (float* arith: +10.9MB/4) lo
    float* AC3 = S1;  float* h3  = S2;

    // ---- prep ----
    pack_w_k<<<(CIN * 2 * O1 + 255) / 256, 256, 0, stream>>>(W1, Wp1, CIN, O1);
    pack_w_k<<<(O1 * 2 * O2 + 255) / 256, 256, 0, stream>>>(W2, Wp2, O1, O2);
    pack_w3t_k<<<(1024 * 256) / 256, 256, 0, stream>>>(W3, Bh3, Bl3);
    norm_w_k<<<1, 256, 0, stream>>>(pw1, pwn1, O1);
    norm_w_k<<<1, 256, 0, stream>>>(pw2, pwn2, O2);
    knn_k<<<B_G, NPG, 0, stream>>>(pos, nbr);

    // ---- level 1 ----
    gemm128_k<0><<<dim3(2 * O1 / 128, N1 / 128), 256, 0, stream>>>(
        x, Wp1, AC1, N1, 2 * O1, CIN, CIN);
    conv_agg_k<<<N1, O1, 0, stream>>>(AC1, nbr, b1, g1, be1, rm1, rv1, h1, O1);
    score_k<<<(N1 + 3) / 4, 256, 0, stream>>>(h1, pwn1, sc1, N1, O1);
    topk_k<<<B_G, 64, 0, stream>>>(sc1, NPG, KP1, gate1, perm1, o2n1);
    gather_k<<<(N2 * O1 + 255) / 256, 256, 0, stream>>>(h1, perm1, gate1, x1p, N2 * O1, 7);
    build_e2_k<<<(N2 * KNN_ + 255) / 256, 256, 0, stream>>>(nbr, perm1, o2n1, e2, N2 * KNN_);

    // ---- level 2 ----
    gemm128_k<1><<<dim3(2 * O2 / 128, N2 / 128), 256, 0, stream>>>(
        x1p, Wp2, AC2, N2, 2 * O2, O1, O1);
    conv_agg_k<<<N2, O2, 0, stream>>>(AC2, e2, b2, g2, be2, rm2, rv2, h2, O2);
    score_k<<<(N2 + 3) / 4, 256, 0, stream>>>(h2, pwn2, sc2, N2, O2);
    topk_k<<<B_G, 64, 0, stream>>>(sc2, KP1, KP2, gate2, perm2, o2n2);
    gather_bf_k<<<(N3 * O2 + 255) / 256, 256, 0, stream>>>(h2, perm2, gate2, x2h, x2l, N3 * O2);
    build_e3_k<<<(N3 * KNN_ + 255) / 256, 256, 0, stream>>>(e2, perm2, o2n2, e3, N3 * KNN_);

    // ---- level 3: split-bf16 MFMA GEMM ----
    gemm3_mfma_k<<<dim3(1024 / 128, N3 / 128), 256, 0, stream>>>(x2h, x2l, Bh3, Bl3, AC3);
    conv_agg_k<<<N3, O3, 0, stream>>>(AC3, e3, b3, g3, be3, rm3, rv3, h3, O3);

    // ---- readout ----
    gmp_k<<<B_G, O3, 0, stream>>>(h3, gmpb);
    mlpc_k<<<B_G, 512, 0, stream>>>(gmpb, Wc1, bc1, gc1, bec1, rmc1, rvc1, z1b);
    final_k<<<1, 256, 0, stream>>>(z1b, Wc2, bc2, gc2, bec2, rmc2, rvc2, out);
}

// Round 8
// 567.041 us; speedup vs baseline: 1.2015x; 1.0617x over previous
//
#include <hip/hip_runtime.h>
#include <hip/hip_bf16.h>
#include <math.h>

#define B_G  256
#define NPG  128
#define KNN_ 4
#define CIN  53
#define N1   32768
#define KP1  103
#define N2   26368   // 256*103
#define KP2  83
#define N3   21248   // 256*83 = 166*128
#define O1   128
#define O2   256
#define O3   512
#define EPSB 1e-5f

typedef __attribute__((ext_vector_type(8))) short bf16x8;
typedef __attribute__((ext_vector_type(4))) float f32x4;

__device__ inline ushort f2bf(float f) {          // RNE float->bf16
    unsigned u = __builtin_bit_cast(unsigned, f);
    u += 0x7fff + ((u >> 16) & 1);
    return (ushort)(u >> 16);
}
__device__ inline float bf2f(ushort h) {
    unsigned u = ((unsigned)h) << 16;
    return __builtin_bit_cast(float, u);
}

// ---------------- weight packing: W[2K][O] -> Wp[K][2O] (A-part | C-part) ---
__global__ void pack_w_k(const float* __restrict__ W, float* __restrict__ Wp,
                         int Kd, int O) {
    int i = blockIdx.x * blockDim.x + threadIdx.x;
    int tot = Kd * 2 * O;
    if (i >= tot) return;
    int k = i / (2 * O), c = i % (2 * O);
    Wp[i] = (c < O) ? W[k * O + c] : W[(Kd + k) * O + (c - O)];
}

// ---- W3 -> transposed packed bf16 hi/lo: BT[n][k], n in [0,1024), k in [0,256)
__global__ void pack_w3t_k(const float* __restrict__ W3,
                           ushort* __restrict__ BhT, ushort* __restrict__ BlT) {
    int i = blockIdx.x * blockDim.x + threadIdx.x;   // 1024*256
    if (i >= 1024 * 256) return;
    int n = i >> 8, k = i & 255;
    float w = (n < 512) ? W3[(size_t)k * 512 + n] : W3[(size_t)(256 + k) * 512 + (n - 512)];
    ushort h = f2bf(w);
    BhT[i] = h;
    BlT[i] = f2bf(w - bf2f(h));
}

// ---------------- normalize pool weight vector ----------------------------
__global__ void norm_w_k(const float* __restrict__ pw, float* __restrict__ pwn, int O) {
    __shared__ float red[256];
    float s = 0.f;
    for (int c = threadIdx.x; c < O; c += 256) s += pw[c] * pw[c];
    red[threadIdx.x] = s;
    __syncthreads();
    for (int st = 128; st > 0; st >>= 1) {
        if (threadIdx.x < st) red[threadIdx.x] += red[threadIdx.x + st];
        __syncthreads();
    }
    float inv = 1.0f / sqrtf(red[0]);
    for (int c = threadIdx.x; c < O; c += 256) pwn[c] = pw[c] * inv;
}

// ---------------- KNN (k=4, per-graph, loop excluded) ---------------------
// Static-register top-4 (no runtime-indexed arrays -> no scratch; rule #20).
__global__ void knn_k(const float* __restrict__ pos, int* __restrict__ nbr) {
    int g = blockIdx.x;
    int i = threadIdx.x;  // 128 threads
    __shared__ float px[NPG], py[NPG], pz[NPG];
    const float* p = pos + (size_t)g * NPG * 3;
    px[i] = p[i * 3 + 0]; py[i] = p[i * 3 + 1]; pz[i] = p[i * 3 + 2];
    __syncthreads();
    float b0 = 1e30f, b1 = 1e30f, b2 = 1e30f, b3 = 1e30f;
    int   i0 = 0, i1 = 0, i2 = 0, i3 = 0;
    float xi = px[i], yi = py[i], zi = pz[i];
    for (int j = 0; j < NPG; ++j) {
        float dx = xi - px[j], dy = yi - py[j], dz = zi - pz[j];
        float d2 = dx * dx + dy * dy + dz * dz;
        if (j != i && d2 < b3) {     // strict <: ties keep lower index (asc. scan)
            if (d2 < b0) {
                b3 = b2; i3 = i2; b2 = b1; i2 = i1; b1 = b0; i1 = i0; b0 = d2; i0 = j;
            } else if (d2 < b1) {
                b3 = b2; i3 = i2; b2 = b1; i2 = i1; b1 = d2; i1 = j;
            } else if (d2 < b2) {
                b3 = b2; i3 = i2; b2 = d2; i2 = j;
            } else {
                b3 = d2; i3 = j;
            }
        }
    }
    int base = (g * NPG + i) * KNN_;
    nbr[base + 0] = g * NPG + i0;
    nbr[base + 1] = g * NPG + i1;
    nbr[base + 2] = g * NPG + i2;
    nbr[base + 3] = g * NPG + i3;
}

// ---------------- fp32 tiled GEMM (levels 1,2) ----------------------------
template <int VEC>
__global__ __launch_bounds__(256) void gemm128_k(
        const float* __restrict__ A, const float* __restrict__ Bm,
        float* __restrict__ Cm, int M, int N, int Kd, int lda) {
    __shared__ float As[16][128];   // transposed: As[k][row]
    __shared__ float Bs[16][128];
    const int tid = threadIdx.x;
    const int row0 = blockIdx.y * 128, col0 = blockIdx.x * 128;
    const int tx = tid & 15;
    const int ty = (tid >> 4) & 15;
    const int s_arow = tid >> 1, s_ak = (tid & 1) * 8;
    const int s_bk = tid >> 4, s_bc = (tid & 15) * 8;
    float acc[8][8] = {};
    for (int k0 = 0; k0 < Kd; k0 += 16) {
        if (VEC) {
            const float4* ap = (const float4*)(A + (size_t)(row0 + s_arow) * lda + k0 + s_ak);
            float4 a0 = ap[0], a1 = ap[1];
            As[s_ak + 0][s_arow] = a0.x; As[s_ak + 1][s_arow] = a0.y;
            As[s_ak + 2][s_arow] = a0.z; As[s_ak + 3][s_arow] = a0.w;
            As[s_ak + 4][s_arow] = a1.x; As[s_ak + 5][s_arow] = a1.y;
            As[s_ak + 6][s_arow] = a1.z; As[s_ak + 7][s_arow] = a1.w;
            const float4* bp = (const float4*)(Bm + (size_t)(k0 + s_bk) * N + col0 + s_bc);
            float4 b0 = bp[0], b1 = bp[1];
            *(float4*)&Bs[s_bk][s_bc] = b0;
            *(float4*)&Bs[s_bk][s_bc + 4] = b1;
        } else {
            #pragma unroll
            for (int s = 0; s < 8; ++s) {
                int kk = s_ak + s;
                As[kk][s_arow] = (k0 + kk < Kd)
                    ? A[(size_t)(row0 + s_arow) * lda + k0 + kk] : 0.f;
            }
            #pragma unroll
            for (int s = 0; s < 8; ++s) {
                Bs[s_bk][s_bc + s] = (k0 + s_bk < Kd)
                    ? Bm[(size_t)(k0 + s_bk) * N + col0 + s_bc + s] : 0.f;
            }
        }
        __syncthreads();
        #pragma unroll
        for (int kk = 0; kk < 16; ++kk) {
            float a[8], b[8];
            *(float4*)&a[0] = *(const float4*)&As[kk][ty * 4];
            *(float4*)&a[4] = *(const float4*)&As[kk][64 + ty * 4];
            *(float4*)&b[0] = *(const float4*)&Bs[kk][tx * 4];
            *(float4*)&b[4] = *(const float4*)&Bs[kk][64 + tx * 4];
            #pragma unroll
            for (int i = 0; i < 8; ++i)
                #pragma unroll
                for (int j = 0; j < 8; ++j)
                    acc[i][j] += a[i] * b[j];
        }
        __syncthreads();
    }
    #pragma unroll
    for (int i = 0; i < 8; ++i) {
        int r = row0 + ((i < 4) ? (ty * 4 + i) : (64 + ty * 4 + (i - 4)));
        size_t base = (size_t)r * N + col0;
        *(float4*)&Cm[base + tx * 4]      = *(float4*)&acc[i][0];
        *(float4*)&Cm[base + 64 + tx * 4] = *(float4*)&acc[i][4];
    }
}

// ---------------- split-bf16 MFMA GEMM (level 3) --------------------------
// C[N3][1024] = A[N3][256] @ B[256][1024];  A given as bf16 hi/lo planes,
// B given transposed bf16 hi/lo BT[n][k].  C ~= Ah*Bh + Ah*Bl + Al*Bh.
#define LDK 40   // 32 k + 8 pad (bf16 elems) -> 80B row stride
__global__ __launch_bounds__(256) void gemm3_mfma_k(
        const ushort* __restrict__ Ah, const ushort* __restrict__ Al,
        const ushort* __restrict__ BhT, const ushort* __restrict__ BlT,
        float* __restrict__ Cm) {
    __shared__ ushort sAh[128][LDK], sAl[128][LDK], sBh[128][LDK], sBl[128][LDK];
    const int tid = threadIdx.x;
    const int row0 = blockIdx.y * 128, col0 = blockIdx.x * 128;
    const int w = tid >> 6, lane = tid & 63;
    const int wr = (w >> 1) * 64, wc = (w & 1) * 64;   // wave's 64x64 sub-tile
    const int fr = lane & 15, fk = (lane >> 4) * 8;    // fragment row/col, k-offset
    const int s_r = tid >> 2, s_c = (tid & 3) * 8;     // staging: 16B per thread per half-tile
    f32x4 acc[4][4] = {};
    for (int k0 = 0; k0 < 256; k0 += 32) {
        {
            size_t ga0 = (size_t)(row0 + s_r) * 256 + k0 + s_c;
            size_t ga1 = (size_t)(row0 + 64 + s_r) * 256 + k0 + s_c;
            *(uint4*)&sAh[s_r][s_c]      = *(const uint4*)&Ah[ga0];
            *(uint4*)&sAh[64 + s_r][s_c] = *(const uint4*)&Ah[ga1];
            *(uint4*)&sAl[s_r][s_c]      = *(const uint4*)&Al[ga0];
            *(uint4*)&sAl[64 + s_r][s_c] = *(const uint4*)&Al[ga1];
            size_t gb0 = (size_t)(col0 + s_r) * 256 + k0 + s_c;
            size_t gb1 = (size_t)(col0 + 64 + s_r) * 256 + k0 + s_c;
            *(uint4*)&sBh[s_r][s_c]      = *(const uint4*)&BhT[gb0];
            *(uint4*)&sBh[64 + s_r][s_c] = *(const uint4*)&BhT[gb1];
            *(uint4*)&sBl[s_r][s_c]      = *(const uint4*)&BlT[gb0];
            *(uint4*)&sBl[64 + s_r][s_c] = *(const uint4*)&BlT[gb1];
        }
        __syncthreads();
        bf16x8 fa_h[4], fa_l[4], fb_h[4], fb_l[4];
        #pragma unroll
        for (int mi = 0; mi < 4; ++mi) {
            fa_h[mi] = *(const bf16x8*)&sAh[wr + mi * 16 + fr][fk];
            fa_l[mi] = *(const bf16x8*)&sAl[wr + mi * 16 + fr][fk];
        }
        #pragma unroll
        for (int ni = 0; ni < 4; ++ni) {
            fb_h[ni] = *(const bf16x8*)&sBh[wc + ni * 16 + fr][fk];
            fb_l[ni] = *(const bf16x8*)&sBl[wc + ni * 16 + fr][fk];
        }
        #pragma unroll
        for (int mi = 0; mi < 4; ++mi)
            #pragma unroll
            for (int ni = 0; ni < 4; ++ni) {
                acc[mi][ni] = __builtin_amdgcn_mfma_f32_16x16x32_bf16(
                    fa_h[mi], fb_h[ni], acc[mi][ni], 0, 0, 0);
                acc[mi][ni] = __builtin_amdgcn_mfma_f32_16x16x32_bf16(
                    fa_h[mi], fb_l[ni], acc[mi][ni], 0, 0, 0);
                acc[mi][ni] = __builtin_amdgcn_mfma_f32_16x16x32_bf16(
                    fa_l[mi], fb_h[ni], acc[mi][ni], 0, 0, 0);
            }
        __syncthreads();
    }
    // C/D layout: col = lane&15, row = (lane>>4)*4 + reg   [m89-verified]
    const int crow = (lane >> 4) * 4, ccol = lane & 15;
    #pragma unroll
    for (int mi = 0; mi < 4; ++mi)
        #pragma unroll
        for (int ni = 0; ni < 4; ++ni) {
            size_t base = (size_t)(row0 + wr + mi * 16 + crow) * 1024
                          + col0 + wc + ni * 16 + ccol;
            #pragma unroll
            for (int r = 0; r < 4; ++r)
                Cm[base + (size_t)r * 1024] = acc[mi][ni][r];
        }
}

// ---------------- EdgeConv aggregation ------------------------------------
__global__ void conv_agg_k(const float* __restrict__ AC, const int* __restrict__ edges,
                           const float* __restrict__ bias, const float* __restrict__ g,
                           const float* __restrict__ be, const float* __restrict__ rm,
                           const float* __restrict__ rv, float* __restrict__ out, int O) {
    int node = blockIdx.x;
    int c = threadIdx.x;            // blockDim == O
    int e0 = node * KNN_;
    int j0 = edges[e0 + 0], j1 = edges[e0 + 1], j2 = edges[e0 + 2], j3 = edges[e0 + 3];
    size_t s2O = (size_t)2 * O;
    float Ai = AC[(size_t)node * s2O + c];
    float Ci = AC[(size_t)node * s2O + O + c];
    float base = Ai - Ci + bias[c];
    float acc = 0.f; int cnt = 0;
    if (j0 >= 0) { acc += fmaxf(base + AC[(size_t)j0 * s2O + O + c], 0.f); ++cnt; }
    if (j1 >= 0) { acc += fmaxf(base + AC[(size_t)j1 * s2O + O + c], 0.f); ++cnt; }
    if (j2 >= 0) { acc += fmaxf(base + AC[(size_t)j2 * s2O + O + c], 0.f); ++cnt; }
    if (j3 >= 0) { acc += fmaxf(base + AC[(size_t)j3 * s2O + O + c], 0.f); ++cnt; }
    float h;
    if (cnt > 0) {
        float m = acc / (float)cnt;
        float sc = g[c] / sqrtf(rv[c] + EPSB);
        h = (m - rm[c]) * sc + be[c];
    } else {
        h = 0.f;
    }
    out[(size_t)node * O + c] = h;
}

// ---------------- pooling score -------------------------------------------
__global__ void score_k(const float* __restrict__ h, const float* __restrict__ pwn,
                        float* __restrict__ sc, int Nl, int O) {
    int wid = (blockIdx.x * blockDim.x + threadIdx.x) >> 6;
    int lane = threadIdx.x & 63;
    if (wid >= Nl) return;
    float s = 0.f;
    for (int c = lane; c < O; c += 64) s += h[(size_t)wid * O + c] * pwn[c];
    #pragma unroll
    for (int off = 32; off > 0; off >>= 1) s += __shfl_down(s, off);
    if (lane == 0) sc[wid] = s;
}

// ---------------- per-graph top-k selection -------------------------------
__global__ void topk_k(const float* __restrict__ sc, int n_l, int k_keep,
                       float* __restrict__ gate, int* __restrict__ perm,
                       int* __restrict__ o2n) {
    int g = blockIdx.x;
    int lane = threadIdx.x;          // 64 threads
    int t0 = lane, t1 = lane + 64;
    float v0 = (t0 < n_l) ? sc[(size_t)g * n_l + t0] : -INFINITY;
    float v1 = (t1 < n_l) ? sc[(size_t)g * n_l + t1] : -INFINITY;
    float ov0 = v0, ov1 = v1;
    int r0 = -1, r1 = -1;
    for (int r = 0; r < k_keep; ++r) {
        float bv; int bi;
        if (v0 >= v1) { bv = v0; bi = t0; } else { bv = v1; bi = t1; }
        #pragma unroll
        for (int m = 32; m > 0; m >>= 1) {
            float wv = __shfl_xor(bv, m);
            int   wi = __shfl_xor(bi, m);
            if (wv > bv || (wv == bv && wi < bi)) { bv = wv; bi = wi; }
        }
        if (bi == t0)      { v0 = -INFINITY; r0 = r; }
        else if (bi == t1) { v1 = -INFINITY; r1 = r; }
    }
    if (t0 < n_l) {
        if (r0 >= 0) {
            int d = g * k_keep + r0;
            perm[d] = g * n_l + t0; gate[d] = tanhf(ov0); o2n[g * n_l + t0] = d;
        } else o2n[g * n_l + t0] = -1;
    }
    if (t1 < n_l) {
        if (r1 >= 0) {
            int d = g * k_keep + r1;
            perm[d] = g * n_l + t1; gate[d] = tanhf(ov1); o2n[g * n_l + t1] = d;
        } else o2n[g * n_l + t1] = -1;
    }
}

// ---------------- gather pooled features (fp32, level 1) ------------------
__global__ void gather_k(const float* __restrict__ h, const int* __restrict__ perm,
                         const float* __restrict__ gate, float* __restrict__ xo,
                         int total, int oshift) {
    int i = blockIdx.x * blockDim.x + threadIdx.x;
    if (i >= total) return;
    int d = i >> oshift, c = i & ((1 << oshift) - 1);
    xo[i] = h[((size_t)perm[d] << oshift) + c] * gate[d];
}

// ---------------- gather pooled features -> bf16 hi/lo (level 2) ----------
__global__ void gather_bf_k(const float* __restrict__ h, const int* __restrict__ perm,
                            const float* __restrict__ gate,
                            ushort* __restrict__ Ah, ushort* __restrict__ Al, int total) {
    int i = blockIdx.x * blockDim.x + threadIdx.x;
    if (i >= total) return;
    int d = i >> 8, c = i & 255;            // O2 == 256
    float v = h[((size_t)perm[d] << 8) + c] * gate[d];
    ushort hh = f2bf(v);
    Ah[i] = hh;
    Al[i] = f2bf(v - bf2f(hh));
}

// ---------------- edge remapping ------------------------------------------
__global__ void build_e2_k(const int* __restrict__ nbr, const int* __restrict__ perm1,
                           const int* __restrict__ o2n1, int* __restrict__ e2, int total) {
    int i = blockIdx.x * blockDim.x + threadIdx.x;
    if (i >= total) return;
    int u = i >> 2, kk = i & 3;
    e2[i] = o2n1[nbr[perm1[u] * KNN_ + kk]];
}

__global__ void build_e3_k(const int* __restrict__ e2, const int* __restrict__ perm2,
                           const int* __restrict__ o2n2, int* __restrict__ e3, int total) {
    int i = blockIdx.x * blockDim.x + threadIdx.x;
    if (i >= total) return;
    int v = i >> 2, kk = i & 3;
    int s1 = e2[perm2[v] * KNN_ + kk];
    e3[i] = (s1 >= 0) ? o2n2[s1] : -1;
}

// ---------------- global mean pool ----------------------------------------
__global__ void gmp_k(const float* __restrict__ h3, float* __restrict__ gmp) {
    int g = blockIdx.x, c = threadIdx.x;  // 512 threads
    float s = 0.f;
    for (int r = 0; r < KP2; ++r) s += h3[((size_t)(g * KP2 + r)) * O3 + c];
    gmp[(size_t)g * O3 + c] = s / (float)KP2;
}

// ---------------- classifier layer 1 --------------------------------------
__global__ void mlpc_k(const float* __restrict__ X, const float* __restrict__ W,
                       const float* __restrict__ bias, const float* __restrict__ g,
                       const float* __restrict__ be, const float* __restrict__ rm,
                       const float* __restrict__ rv, float* __restrict__ out) {
    int b = blockIdx.x, o = threadIdx.x;  // 512 threads
    __shared__ float xr[512];
    xr[o] = X[(size_t)b * 512 + o];
    __syncthreads();
    float acc = bias[o];
    for (int k = 0; k < 512; ++k) acc += xr[k] * W[(size_t)k * 512 + o];
    acc = fmaxf(acc, 0.f);
    float s = g[o] / sqrtf(rv[o] + EPSB);
    out[(size_t)b * 512 + o] = (acc - rm[o]) * s + be[o];
}

// ---------------- classifier layer 2 + sigmoid ----------------------------
__global__ void final_k(const float* __restrict__ z1, const float* __restrict__ Wc2,
                        const float* __restrict__ bc2, const float* __restrict__ gc2,
                        const float* __restrict__ bec2, const float* __restrict__ rmc2,
                        const float* __restrict__ rvc2, float* __restrict__ out) {
    int b = blockIdx.x * blockDim.x + threadIdx.x;
    if (b >= B_G) return;
    float acc = bc2[0];
    for (int k = 0; k < 512; ++k) acc += z1[(size_t)b * 512 + k] * Wc2[k];
    acc = fmaxf(acc, 0.f);
    float s = gc2[0] / sqrtf(rvc2[0] + EPSB);
    float z = (acc - rmc2[0]) * s + bec2[0];
    out[b] = 1.f / (1.f + expf(-z));
}

// ==========================================================================
extern "C" void kernel_launch(void* const* d_in, const int* in_sizes, int n_in,
                              void* d_out, int out_size, void* d_ws, size_t ws_size,
                              hipStream_t stream) {
    const float* x    = (const float*)d_in[0];
    const float* pos  = (const float*)d_in[1];
    const float* W1   = (const float*)d_in[2];
    const float* b1   = (const float*)d_in[3];
    const float* g1   = (const float*)d_in[4];
    const float* be1  = (const float*)d_in[5];
    const float* rm1  = (const float*)d_in[6];
    const float* rv1  = (const float*)d_in[7];
    const float* pw1  = (const float*)d_in[8];
    const float* W2   = (const float*)d_in[9];
    const float* b2   = (const float*)d_in[10];
    const float* g2   = (const float*)d_in[11];
    const float* be2  = (const float*)d_in[12];
    const float* rm2  = (const float*)d_in[13];
    const float* rv2  = (const float*)d_in[14];
    const float* pw2  = (const float*)d_in[15];
    const float* W3   = (const float*)d_in[16];
    const float* b3   = (const float*)d_in[17];
    const float* g3   = (const float*)d_in[18];
    const float* be3  = (const float*)d_in[19];
    const float* rm3  = (const float*)d_in[20];
    const float* rv3  = (const float*)d_in[21];
    const float* Wc1  = (const float*)d_in[22];
    const float* bc1  = (const float*)d_in[23];
    const float* gc1  = (const float*)d_in[24];
    const float* bec1 = (const float*)d_in[25];
    const float* rmc1 = (const float*)d_in[26];
    const float* rvc1 = (const float*)d_in[27];
    const float* Wc2  = (const float*)d_in[28];
    const float* bc2  = (const float*)d_in[29];
    const float* gc2  = (const float*)d_in[30];
    const float* bec2 = (const float*)d_in[31];
    const float* rmc2 = (const float*)d_in[32];
    const float* rvc2 = (const float*)d_in[33];
    float* out = (float*)d_out;

    // ---- workspace layout ----
    char* ws = (char*)d_ws;
    size_t off = 0;
    auto take = [&](size_t bytes) { size_t o = off; off = (off + bytes + 255) & ~(size_t)255; return o; };
    size_t o_nbr   = take((size_t)N1 * KNN_ * 4);
    size_t o_perm1 = take((size_t)N2 * 4);
    size_t o_o2n1  = take((size_t)N1 * 4);
    size_t o_perm2 = take((size_t)N3 * 4);
    size_t o_o2n2  = take((size_t)N2 * 4);
    size_t o_e2    = take((size_t)N2 * KNN_ * 4);
    size_t o_e3    = take((size_t)N3 * KNN_ * 4);
    size_t o_pwn1  = take((size_t)O1 * 4);
    size_t o_pwn2  = take((size_t)O2 * 4);
    size_t o_sc1   = take((size_t)N1 * 4);
    size_t o_sc2   = take((size_t)N2 * 4);
    size_t o_gate1 = take((size_t)N2 * 4);
    size_t o_gate2 = take((size_t)N3 * 4);
    size_t o_Wp1   = take((size_t)CIN * 2 * O1 * 4);
    size_t o_Wp2   = take((size_t)O1 * 2 * O2 * 4);
    size_t o_Bh3   = take((size_t)1024 * 256 * 2);   // W3 bf16 hi (transposed)
    size_t o_Bl3   = take((size_t)1024 * 256 * 2);   // W3 bf16 lo
    size_t o_gmp   = take((size_t)B_G * O3 * 4);
    size_t o_z1    = take((size_t)B_G * O3 * 4);
    size_t o_S1    = take((size_t)N3 * 2 * O3 * 4);   // max: AC3 = 21248*1024 f32
    size_t o_S2    = take((size_t)N2 * 2 * O2 * 4);   // max: AC2 = 26368*512 f32

    int*   nbr   = (int*)(ws + o_nbr);
    int*   perm1 = (int*)(ws + o_perm1);
    int*   o2n1  = (int*)(ws + o_o2n1);
    int*   perm2 = (int*)(ws + o_perm2);
    int*   o2n2  = (int*)(ws + o_o2n2);
    int*   e2    = (int*)(ws + o_e2);
    int*   e3    = (int*)(ws + o_e3);
    float* pwn1  = (float*)(ws + o_pwn1);
    float* pwn2  = (float*)(ws + o_pwn2);
    float* sc1   = (float*)(ws + o_sc1);
    float* sc2   = (float*)(ws + o_sc2);
    float* gate1 = (float*)(ws + o_gate1);
    float* gate2 = (float*)(ws + o_gate2);
    float* Wp1   = (float*)(ws + o_Wp1);
    float* Wp2   = (float*)(ws + o_Wp2);
    ushort* Bh3  = (ushort*)(ws + o_Bh3);
    ushort* Bl3  = (ushort*)(ws + o_Bl3);
    float* gmpb  = (float*)(ws + o_gmp);
    float* z1b   = (float*)(ws + o_z1);
    float* S1    = (float*)(ws + o_S1);
    float* S2    = (float*)(ws + o_S2);

    float* AC1 = S1;  float* h1  = S2;
    float* x1p = S1;  float* AC2 = S2;
    float* h2  = S1;
    ushort* x2h = (ushort*)S2;                       // 21248*256 bf16 hi
    ushort* x2l = (ushort*)(S2 + (size_t)N3 * 256);  // lo plane
    float* AC3 = S1;  float* h3  = S2;

    // ---- prep ----
    pack_w_k<<<(CIN * 2 * O1 + 255) / 256, 256, 0, stream>>>(W1, Wp1, CIN, O1);
    pack_w_k<<<(O1 * 2 * O2 + 255) / 256, 256, 0, stream>>>(W2, Wp2, O1, O2);
    pack_w3t_k<<<(1024 * 256) / 256, 256, 0, stream>>>(W3, Bh3, Bl3);
    norm_w_k<<<1, 256, 0, stream>>>(pw1, pwn1, O1);
    norm_w_k<<<1, 256, 0, stream>>>(pw2, pwn2, O2);
    knn_k<<<B_G, NPG, 0, stream>>>(pos, nbr);

    // ---- level 1 ----
    gemm128_k<0><<<dim3(2 * O1 / 128, N1 / 128), 256, 0, stream>>>(
        x, Wp1, AC1, N1, 2 * O1, CIN, CIN);
    conv_agg_k<<<N1, O1, 0, stream>>>(AC1, nbr, b1, g1, be1, rm1, rv1, h1, O1);
    score_k<<<(N1 + 3) / 4, 256, 0, stream>>>(h1, pwn1, sc1, N1, O1);
    topk_k<<<B_G, 64, 0, stream>>>(sc1, NPG, KP1, gate1, perm1, o2n1);
    gather_k<<<(N2 * O1 + 255) / 256, 256, 0, stream>>>(h1, perm1, gate1, x1p, N2 * O1, 7);
    build_e2_k<<<(N2 * KNN_ + 255) / 256, 256, 0, stream>>>(nbr, perm1, o2n1, e2, N2 * KNN_);

    // ---- level 2 ----
    gemm128_k<1><<<dim3(2 * O2 / 128, N2 / 128), 256, 0, stream>>>(
        x1p, Wp2, AC2, N2, 2 * O2, O1, O1);
    conv_agg_k<<<N2, O2, 0, stream>>>(AC2, e2, b2, g2, be2, rm2, rv2, h2, O2);
    score_k<<<(N2 + 3) / 4, 256, 0, stream>>>(h2, pwn2, sc2, N2, O2);
    topk_k<<<B_G, 64, 0, stream>>>(sc2, KP1, KP2, gate2, perm2, o2n2);
    gather_bf_k<<<(N3 * O2 + 255) / 256, 256, 0, stream>>>(h2, perm2, gate2, x2h, x2l, N3 * O2);
    build_e3_k<<<(N3 * KNN_ + 255) / 256, 256, 0, stream>>>(e2, perm2, o2n2, e3, N3 * KNN_);

    // ---- level 3: split-bf16 MFMA GEMM ----
    gemm3_mfma_k<<<dim3(1024 / 128, N3 / 128), 256, 0, stream>>>(x2h, x2l, Bh3, Bl3, AC3);
    conv_agg_k<<<N3, O3, 0, stream>>>(AC3, e3, b3, g3, be3, rm3, rv3, h3, O3);

    // ---- readout ----
    gmp_k<<<B_G, O3, 0, stream>>>(h3, gmpb);
    mlpc_k<<<B_G, 512, 0, stream>>>(gmpb, Wc1, bc1, gc1, bec1, rmc1, rvc1, z1b);
    final_k<<<1, 256, 0, stream>>>(z1b, Wc2, bc2, gc2, bec2, rmc2, rvc2, out);
}

// Round 11
// 479.982 us; speedup vs baseline: 1.4194x; 1.1814x over previous
//
#include <hip/hip_runtime.h>
#include <hip/hip_bf16.h>
#include <math.h>

#define B_G  256
#define NPG  128
#define KNN_ 4
#define CIN  53
#define N1   32768
#define KP1  103
#define N2   26368   // 256*103
#define KP2  83
#define N3   21248   // 256*83 = 166*128
#define O1   128
#define O2   256
#define O3   512
#define EPSB 1e-5f

typedef __attribute__((ext_vector_type(8))) short bf16x8;
typedef __attribute__((ext_vector_type(4))) float f32x4;

__device__ inline ushort f2bf(float f) {          // RNE float->bf16
    unsigned u = __builtin_bit_cast(unsigned, f);
    u += 0x7fff + ((u >> 16) & 1);
    return (ushort)(u >> 16);
}
__device__ inline float bf2f(ushort h) {
    unsigned u = ((unsigned)h) << 16;
    return __builtin_bit_cast(float, u);
}

// ---------------- weight packing: W[2K][O] -> Wp[K][2O] (A-part | C-part) ---
__global__ void pack_w_k(const float* __restrict__ W, float* __restrict__ Wp,
                         int Kd, int O) {
    int i = blockIdx.x * blockDim.x + threadIdx.x;
    int tot = Kd * 2 * O;
    if (i >= tot) return;
    int k = i / (2 * O), c = i % (2 * O);
    Wp[i] = (c < O) ? W[k * O + c] : W[(Kd + k) * O + (c - O)];
}

// ---- W3 -> transposed packed bf16 hi/lo: BT[n][k], n in [0,1024), k in [0,256)
__global__ void pack_w3t_k(const float* __restrict__ W3,
                           ushort* __restrict__ BhT, ushort* __restrict__ BlT) {
    int i = blockIdx.x * blockDim.x + threadIdx.x;   // 1024*256
    if (i >= 1024 * 256) return;
    int n = i >> 8, k = i & 255;
    float w = (n < 512) ? W3[(size_t)k * 512 + n] : W3[(size_t)(256 + k) * 512 + (n - 512)];
    ushort h = f2bf(w);
    BhT[i] = h;
    BlT[i] = f2bf(w - bf2f(h));
}

// ---------------- normalize pool weight vector ----------------------------
__global__ void norm_w_k(const float* __restrict__ pw, float* __restrict__ pwn, int O) {
    __shared__ float red[256];
    float s = 0.f;
    for (int c = threadIdx.x; c < O; c += 256) s += pw[c] * pw[c];
    red[threadIdx.x] = s;
    __syncthreads();
    for (int st = 128; st > 0; st >>= 1) {
        if (threadIdx.x < st) red[threadIdx.x] += red[threadIdx.x + st];
        __syncthreads();
    }
    float inv = 1.0f / sqrtf(red[0]);
    for (int c = threadIdx.x; c < O; c += 256) pwn[c] = pw[c] * inv;
}

// ---------------- KNN (k=4, per-graph, loop excluded) ---------------------
// Static-register top-4 (no runtime-indexed arrays -> no scratch; rule #20).
__global__ void knn_k(const float* __restrict__ pos, int* __restrict__ nbr) {
    int g = blockIdx.x;
    int i = threadIdx.x;  // 128 threads
    __shared__ float px[NPG], py[NPG], pz[NPG];
    const float* p = pos + (size_t)g * NPG * 3;
    px[i] = p[i * 3 + 0]; py[i] = p[i * 3 + 1]; pz[i] = p[i * 3 + 2];
    __syncthreads();
    float b0 = 1e30f, b1 = 1e30f, b2 = 1e30f, b3 = 1e30f;
    int   i0 = 0, i1 = 0, i2 = 0, i3 = 0;
    float xi = px[i], yi = py[i], zi = pz[i];
    for (int j = 0; j < NPG; ++j) {
        float dx = xi - px[j], dy = yi - py[j], dz = zi - pz[j];
        float d2 = dx * dx + dy * dy + dz * dz;
        if (j != i && d2 < b3) {     // strict <: ties keep lower index (asc. scan)
            if (d2 < b0) {
                b3 = b2; i3 = i2; b2 = b1; i2 = i1; b1 = b0; i1 = i0; b0 = d2; i0 = j;
            } else if (d2 < b1) {
                b3 = b2; i3 = i2; b2 = b1; i2 = i1; b1 = d2; i1 = j;
            } else if (d2 < b2) {
                b3 = b2; i3 = i2; b2 = d2; i2 = j;
            } else {
                b3 = d2; i3 = j;
            }
        }
    }
    int base = (g * NPG + i) * KNN_;
    nbr[base + 0] = g * NPG + i0;
    nbr[base + 1] = g * NPG + i1;
    nbr[base + 2] = g * NPG + i2;
    nbr[base + 3] = g * NPG + i3;
}

// ---------------- fp32 tiled GEMM (levels 1,2) ----------------------------
template <int VEC>
__global__ __launch_bounds__(256) void gemm128_k(
        const float* __restrict__ A, const float* __restrict__ Bm,
        float* __restrict__ Cm, int M, int N, int Kd, int lda) {
    __shared__ float As[16][128];   // transposed: As[k][row]
    __shared__ float Bs[16][128];
    const int tid = threadIdx.x;
    const int row0 = blockIdx.y * 128, col0 = blockIdx.x * 128;
    const int tx = tid & 15;
    const int ty = (tid >> 4) & 15;
    const int s_arow = tid >> 1, s_ak = (tid & 1) * 8;
    const int s_bk = tid >> 4, s_bc = (tid & 15) * 8;
    float acc[8][8] = {};
    for (int k0 = 0; k0 < Kd; k0 += 16) {
        if (VEC) {
            const float4* ap = (const float4*)(A + (size_t)(row0 + s_arow) * lda + k0 + s_ak);
            float4 a0 = ap[0], a1 = ap[1];
            As[s_ak + 0][s_arow] = a0.x; As[s_ak + 1][s_arow] = a0.y;
            As[s_ak + 2][s_arow] = a0.z; As[s_ak + 3][s_arow] = a0.w;
            As[s_ak + 4][s_arow] = a1.x; As[s_ak + 5][s_arow] = a1.y;
            As[s_ak + 6][s_arow] = a1.z; As[s_ak + 7][s_arow] = a1.w;
            const float4* bp = (const float4*)(Bm + (size_t)(k0 + s_bk) * N + col0 + s_bc);
            float4 b0 = bp[0], b1 = bp[1];
            *(float4*)&Bs[s_bk][s_bc] = b0;
            *(float4*)&Bs[s_bk][s_bc + 4] = b1;
        } else {
            #pragma unroll
            for (int s = 0; s < 8; ++s) {
                int kk = s_ak + s;
                As[kk][s_arow] = (k0 + kk < Kd)
                    ? A[(size_t)(row0 + s_arow) * lda + k0 + kk] : 0.f;
            }
            #pragma unroll
            for (int s = 0; s < 8; ++s) {
                Bs[s_bk][s_bc + s] = (k0 + s_bk < Kd)
                    ? Bm[(size_t)(k0 + s_bk) * N + col0 + s_bc + s] : 0.f;
            }
        }
        __syncthreads();
        #pragma unroll
        for (int kk = 0; kk < 16; ++kk) {
            float a[8], b[8];
            *(float4*)&a[0] = *(const float4*)&As[kk][ty * 4];
            *(float4*)&a[4] = *(const float4*)&As[kk][64 + ty * 4];
            *(float4*)&b[0] = *(const float4*)&Bs[kk][tx * 4];
            *(float4*)&b[4] = *(const float4*)&Bs[kk][64 + tx * 4];
            #pragma unroll
            for (int i = 0; i < 8; ++i)
                #pragma unroll
                for (int j = 0; j < 8; ++j)
                    acc[i][j] += a[i] * b[j];
        }
        __syncthreads();
    }
    #pragma unroll
    for (int i = 0; i < 8; ++i) {
        int r = row0 + ((i < 4) ? (ty * 4 + i) : (64 + ty * 4 + (i - 4)));
        size_t base = (size_t)r * N + col0;
        *(float4*)&Cm[base + tx * 4]      = *(float4*)&acc[i][0];
        *(float4*)&Cm[base + 64 + tx * 4] = *(float4*)&acc[i][4];
    }
}

// ---------------- split-bf16 MFMA GEMM (level 3) --------------------------
// C[N3][1024] = A[N3][256] @ B[256][1024];  A given as bf16 hi/lo planes,
// B given transposed bf16 hi/lo BT[n][k].  C ~= Ah*Bh + Ah*Bl + Al*Bh.
#define LDK 40   // 32 k + 8 pad (bf16 elems) -> 80B row stride
__global__ __launch_bounds__(256) void gemm3_mfma_k(
        const ushort* __restrict__ Ah, const ushort* __restrict__ Al,
        const ushort* __restrict__ BhT, const ushort* __restrict__ BlT,
        float* __restrict__ Cm) {
    __shared__ ushort sAh[128][LDK], sAl[128][LDK], sBh[128][LDK], sBl[128][LDK];
    const int tid = threadIdx.x;
    const int row0 = blockIdx.y * 128, col0 = blockIdx.x * 128;
    const int w = tid >> 6, lane = tid & 63;
    const int wr = (w >> 1) * 64, wc = (w & 1) * 64;   // wave's 64x64 sub-tile
    const int fr = lane & 15, fk = (lane >> 4) * 8;    // fragment row/col, k-offset
    const int s_r = tid >> 2, s_c = (tid & 3) * 8;     // staging: 16B per thread per half-tile
    f32x4 acc[4][4] = {};
    for (int k0 = 0; k0 < 256; k0 += 32) {
        {
            size_t ga0 = (size_t)(row0 + s_r) * 256 + k0 + s_c;
            size_t ga1 = (size_t)(row0 + 64 + s_r) * 256 + k0 + s_c;
            *(uint4*)&sAh[s_r][s_c]      = *(const uint4*)&Ah[ga0];
            *(uint4*)&sAh[64 + s_r][s_c] = *(const uint4*)&Ah[ga1];
            *(uint4*)&sAl[s_r][s_c]      = *(const uint4*)&Al[ga0];
            *(uint4*)&sAl[64 + s_r][s_c] = *(const uint4*)&Al[ga1];
            size_t gb0 = (size_t)(col0 + s_r) * 256 + k0 + s_c;
            size_t gb1 = (size_t)(col0 + 64 + s_r) * 256 + k0 + s_c;
            *(uint4*)&sBh[s_r][s_c]      = *(const uint4*)&BhT[gb0];
            *(uint4*)&sBh[64 + s_r][s_c] = *(const uint4*)&BhT[gb1];
            *(uint4*)&sBl[s_r][s_c]      = *(const uint4*)&BlT[gb0];
            *(uint4*)&sBl[64 + s_r][s_c] = *(const uint4*)&BlT[gb1];
        }
        __syncthreads();
        bf16x8 fa_h[4], fa_l[4], fb_h[4], fb_l[4];
        #pragma unroll
        for (int mi = 0; mi < 4; ++mi) {
            fa_h[mi] = *(const bf16x8*)&sAh[wr + mi * 16 + fr][fk];
            fa_l[mi] = *(const bf16x8*)&sAl[wr + mi * 16 + fr][fk];
        }
        #pragma unroll
        for (int ni = 0; ni < 4; ++ni) {
            fb_h[ni] = *(const bf16x8*)&sBh[wc + ni * 16 + fr][fk];
            fb_l[ni] = *(const bf16x8*)&sBl[wc + ni * 16 + fr][fk];
        }
        #pragma unroll
        for (int mi = 0; mi < 4; ++mi)
            #pragma unroll
            for (int ni = 0; ni < 4; ++ni) {
                acc[mi][ni] = __builtin_amdgcn_mfma_f32_16x16x32_bf16(
                    fa_h[mi], fb_h[ni], acc[mi][ni], 0, 0, 0);
                acc[mi][ni] = __builtin_amdgcn_mfma_f32_16x16x32_bf16(
                    fa_h[mi], fb_l[ni], acc[mi][ni], 0, 0, 0);
                acc[mi][ni] = __builtin_amdgcn_mfma_f32_16x16x32_bf16(
                    fa_l[mi], fb_h[ni], acc[mi][ni], 0, 0, 0);
            }
        __syncthreads();
    }
    // C/D layout: col = lane&15, row = (lane>>4)*4 + reg   [m89-verified]
    const int crow = (lane >> 4) * 4, ccol = lane & 15;
    #pragma unroll
    for (int mi = 0; mi < 4; ++mi)
        #pragma unroll
        for (int ni = 0; ni < 4; ++ni) {
            size_t base = (size_t)(row0 + wr + mi * 16 + crow) * 1024
                          + col0 + wc + ni * 16 + ccol;
            #pragma unroll
            for (int r = 0; r < 4; ++r)
                Cm[base + (size_t)r * 1024] = acc[mi][ni][r];
        }
}

// ---------------- EdgeConv aggregation ------------------------------------
__global__ void conv_agg_k(const float* __restrict__ AC, const int* __restrict__ edges,
                           const float* __restrict__ bias, const float* __restrict__ g,
                           const float* __restrict__ be, const float* __restrict__ rm,
                           const float* __restrict__ rv, float* __restrict__ out, int O) {
    int node = blockIdx.x;
    int c = threadIdx.x;            // blockDim == O
    int e0 = node * KNN_;
    int j0 = edges[e0 + 0], j1 = edges[e0 + 1], j2 = edges[e0 + 2], j3 = edges[e0 + 3];
    size_t s2O = (size_t)2 * O;
    float Ai = AC[(size_t)node * s2O + c];
    float Ci = AC[(size_t)node * s2O + O + c];
    float base = Ai - Ci + bias[c];
    float acc = 0.f; int cnt = 0;
    if (j0 >= 0) { acc += fmaxf(base + AC[(size_t)j0 * s2O + O + c], 0.f); ++cnt; }
    if (j1 >= 0) { acc += fmaxf(base + AC[(size_t)j1 * s2O + O + c], 0.f); ++cnt; }
    if (j2 >= 0) { acc += fmaxf(base + AC[(size_t)j2 * s2O + O + c], 0.f); ++cnt; }
    if (j3 >= 0) { acc += fmaxf(base + AC[(size_t)j3 * s2O + O + c], 0.f); ++cnt; }
    float h;
    if (cnt > 0) {
        float m = acc / (float)cnt;
        float sc = g[c] / sqrtf(rv[c] + EPSB);
        h = (m - rm[c]) * sc + be[c];
    } else {
        h = 0.f;
    }
    out[(size_t)node * O + c] = h;
}

// ---------------- pooling score -------------------------------------------
__global__ void score_k(const float* __restrict__ h, const float* __restrict__ pwn,
                        float* __restrict__ sc, int Nl, int O) {
    int wid = (blockIdx.x * blockDim.x + threadIdx.x) >> 6;
    int lane = threadIdx.x & 63;
    if (wid >= Nl) return;
    float s = 0.f;
    for (int c = lane; c < O; c += 64) s += h[(size_t)wid * O + c] * pwn[c];
    #pragma unroll
    for (int off = 32; off > 0; off >>= 1) s += __shfl_down(s, off);
    if (lane == 0) sc[wid] = s;
}

// ---------------- per-graph top-k via rank (parallel, no serial rounds) ---
// rank(t) = #{ j : s_j > s_t  or (s_j == s_t and j < t) }  == jax.lax.top_k
// stable descending order position.  rank < k_keep  <=>  selected, and rank
// IS the destination slot.  One 128-thread block per graph.
__global__ void topk_rank_k(const float* __restrict__ sc, int n_l, int k_keep,
                            float* __restrict__ gate, int* __restrict__ perm,
                            int* __restrict__ o2n) {
    int g = blockIdx.x;
    int t = threadIdx.x;             // 128 threads, t < n_l active
    __shared__ float s[NPG];
    if (t < n_l) s[t] = sc[(size_t)g * n_l + t];
    __syncthreads();
    if (t >= n_l) return;
    float v = s[t];
    int rank = 0;
    for (int j = 0; j < n_l; ++j) {
        float vj = s[j];
        rank += (vj > v || (vj == v && j < t)) ? 1 : 0;
    }
    int gi = g * n_l + t;
    if (rank < k_keep) {
        int d = g * k_keep + rank;
        perm[d] = gi;
        gate[d] = tanhf(v);
        o2n[gi] = d;
    } else {
        o2n[gi] = -1;
    }
}

// ---------------- gather pooled features (fp32, level 1) ------------------
__global__ void gather_k(const float* __restrict__ h, const int* __restrict__ perm,
                         const float* __restrict__ gate, float* __restrict__ xo,
                         int total, int oshift) {
    int i = blockIdx.x * blockDim.x + threadIdx.x;
    if (i >= total) return;
    int d = i >> oshift, c = i & ((1 << oshift) - 1);
    xo[i] = h[((size_t)perm[d] << oshift) + c] * gate[d];
}

// ---------------- gather pooled features -> bf16 hi/lo (level 2) ----------
__global__ void gather_bf_k(const float* __restrict__ h, const int* __restrict__ perm,
                            const float* __restrict__ gate,
                            ushort* __restrict__ Ah, ushort* __restrict__ Al, int total) {
    int i = blockIdx.x * blockDim.x + threadIdx.x;
    if (i >= total) return;
    int d = i >> 8, c = i & 255;            // O2 == 256
    float v = h[((size_t)perm[d] << 8) + c] * gate[d];
    ushort hh = f2bf(v);
    Ah[i] = hh;
    Al[i] = f2bf(v - bf2f(hh));
}

// ---------------- edge remapping ------------------------------------------
__global__ void build_e2_k(const int* __restrict__ nbr, const int* __restrict__ perm1,
                           const int* __restrict__ o2n1, int* __restrict__ e2, int total) {
    int i = blockIdx.x * blockDim.x + threadIdx.x;
    if (i >= total) return;
    int u = i >> 2, kk = i & 3;
    e2[i] = o2n1[nbr[perm1[u] * KNN_ + kk]];
}

__global__ void build_e3_k(const int* __restrict__ e2, const int* __restrict__ perm2,
                           const int* __restrict__ o2n2, int* __restrict__ e3, int total) {
    int i = blockIdx.x * blockDim.x + threadIdx.x;
    if (i >= total) return;
    int v = i >> 2, kk = i & 3;
    int s1 = e2[perm2[v] * KNN_ + kk];
    e3[i] = (s1 >= 0) ? o2n2[s1] : -1;
}

// ---------------- global mean pool ----------------------------------------
__global__ void gmp_k(const float* __restrict__ h3, float* __restrict__ gmp) {
    int g = blockIdx.x, c = threadIdx.x;  // 512 threads
    float s = 0.f;
    for (int r = 0; r < KP2; ++r) s += h3[((size_t)(g * KP2 + r)) * O3 + c];
    gmp[(size_t)g * O3 + c] = s / (float)KP2;
}

// ---------------- classifier layer 1 --------------------------------------
__global__ void mlpc_k(const float* __restrict__ X, const float* __restrict__ W,
                       const float* __restrict__ bias, const float* __restrict__ g,
                       const float* __restrict__ be, const float* __restrict__ rm,
                       const float* __restrict__ rv, float* __restrict__ out) {
    int b = blockIdx.x, o = threadIdx.x;  // 512 threads
    __shared__ float xr[512];
    xr[o] = X[(size_t)b * 512 + o];
    __syncthreads();
    float acc = bias[o];
    for (int k = 0; k < 512; ++k) acc += xr[k] * W[(size_t)k * 512 + o];
    acc = fmaxf(acc, 0.f);
    float s = g[o] / sqrtf(rv[o] + EPSB);
    out[(size_t)b * 512 + o] = (acc - rm[o]) * s + be[o];
}

// ---------------- classifier layer 2 + sigmoid ----------------------------
__global__ void final_k(const float* __restrict__ z1, const float* __restrict__ Wc2,
                        const float* __restrict__ bc2, const float* __restrict__ gc2,
                        const float* __restrict__ bec2, const float* __restrict__ rmc2,
                        const float* __restrict__ rvc2, float* __restrict__ out) {
    int b = blockIdx.x * blockDim.x + threadIdx.x;
    if (b >= B_G) return;
    float acc = bc2[0];
    for (int k = 0; k < 512; ++k) acc += z1[(size_t)b * 512 + k] * Wc2[k];
    acc = fmaxf(acc, 0.f);
    float s = gc2[0] / sqrtf(rvc2[0] + EPSB);
    float z = (acc - rmc2[0]) * s + bec2[0];
    out[b] = 1.f / (1.f + expf(-z));
}

// ==========================================================================
extern "C" void kernel_launch(void* const* d_in, const int* in_sizes, int n_in,
                              void* d_out, int out_size, void* d_ws, size_t ws_size,
                              hipStream_t stream) {
    const float* x    = (const float*)d_in[0];
    const float* pos  = (const float*)d_in[1];
    const float* W1   = (const float*)d_in[2];
    const float* b1   = (const float*)d_in[3];
    const float* g1   = (const float*)d_in[4];
    const float* be1  = (const float*)d_in[5];
    const float* rm1  = (const float*)d_in[6];
    const float* rv1  = (const float*)d_in[7];
    const float* pw1  = (const float*)d_in[8];
    const float* W2   = (const float*)d_in[9];
    const float* b2   = (const float*)d_in[10];
    const float* g2   = (const float*)d_in[11];
    const float* be2  = (const float*)d_in[12];
    const float* rm2  = (const float*)d_in[13];
    const float* rv2  = (const float*)d_in[14];
    const float* pw2  = (const float*)d_in[15];
    const float* W3   = (const float*)d_in[16];
    const float* b3   = (const float*)d_in[17];
    const float* g3   = (const float*)d_in[18];
    const float* be3  = (const float*)d_in[19];
    const float* rm3  = (const float*)d_in[20];
    const float* rv3  = (const float*)d_in[21];
    const float* Wc1  = (const float*)d_in[22];
    const float* bc1  = (const float*)d_in[23];
    const float* gc1  = (const float*)d_in[24];
    const float* bec1 = (const float*)d_in[25];
    const float* rmc1 = (const float*)d_in[26];
    const float* rvc1 = (const float*)d_in[27];
    const float* Wc2  = (const float*)d_in[28];
    const float* bc2  = (const float*)d_in[29];
    const float* gc2  = (const float*)d_in[30];
    const float* bec2 = (const float*)d_in[31];
    const float* rmc2 = (const float*)d_in[32];
    const float* rvc2 = (const float*)d_in[33];
    float* out = (float*)d_out;

    // ---- workspace layout ----
    char* ws = (char*)d_ws;
    size_t off = 0;
    auto take = [&](size_t bytes) { size_t o = off; off = (off + bytes + 255) & ~(size_t)255; return o; };
    size_t o_nbr   = take((size_t)N1 * KNN_ * 4);
    size_t o_perm1 = take((size_t)N2 * 4);
    size_t o_o2n1  = take((size_t)N1 * 4);
    size_t o_perm2 = take((size_t)N3 * 4);
    size_t o_o2n2  = take((size_t)N2 * 4);
    size_t o_e2    = take((size_t)N2 * KNN_ * 4);
    size_t o_e3    = take((size_t)N3 * KNN_ * 4);
    size_t o_pwn1  = take((size_t)O1 * 4);
    size_t o_pwn2  = take((size_t)O2 * 4);
    size_t o_sc1   = take((size_t)N1 * 4);
    size_t o_sc2   = take((size_t)N2 * 4);
    size_t o_gate1 = take((size_t)N2 * 4);
    size_t o_gate2 = take((size_t)N3 * 4);
    size_t o_Wp1   = take((size_t)CIN * 2 * O1 * 4);
    size_t o_Wp2   = take((size_t)O1 * 2 * O2 * 4);
    size_t o_Bh3   = take((size_t)1024 * 256 * 2);   // W3 bf16 hi (transposed)
    size_t o_Bl3   = take((size_t)1024 * 256 * 2);   // W3 bf16 lo
    size_t o_gmp   = take((size_t)B_G * O3 * 4);
    size_t o_z1    = take((size_t)B_G * O3 * 4);
    size_t o_S1    = take((size_t)N3 * 2 * O3 * 4);   // max: AC3 = 21248*1024 f32
    size_t o_S2    = take((size_t)N2 * 2 * O2 * 4);   // max: AC2 = 26368*512 f32

    int*   nbr   = (int*)(ws + o_nbr);
    int*   perm1 = (int*)(ws + o_perm1);
    int*   o2n1  = (int*)(ws + o_o2n1);
    int*   perm2 = (int*)(ws + o_perm2);
    int*   o2n2  = (int*)(ws + o_o2n2);
    int*   e2    = (int*)(ws + o_e2);
    int*   e3    = (int*)(ws + o_e3);
    float* pwn1  = (float*)(ws + o_pwn1);
    float* pwn2  = (float*)(ws + o_pwn2);
    float* sc1   = (float*)(ws + o_sc1);
    float* sc2   = (float*)(ws + o_sc2);
    float* gate1 = (float*)(ws + o_gate1);
    float* gate2 = (float*)(ws + o_gate2);
    float* Wp1   = (float*)(ws + o_Wp1);
    float* Wp2   = (float*)(ws + o_Wp2);
    ushort* Bh3  = (ushort*)(ws + o_Bh3);
    ushort* Bl3  = (ushort*)(ws + o_Bl3);
    float* gmpb  = (float*)(ws + o_gmp);
    float* z1b   = (float*)(ws + o_z1);
    float* S1    = (float*)(ws + o_S1);
    float* S2    = (float*)(ws + o_S2);

    float* AC1 = S1;  float* h1  = S2;
    float* x1p = S1;  float* AC2 = S2;
    float* h2  = S1;
    ushort* x2h = (ushort*)S2;                       // 21248*256 bf16 hi
    ushort* x2l = (ushort*)(S2 + (size_t)N3 * 256);  // lo plane
    float* AC3 = S1;  float* h3  = S2;

    // ---- prep ----
    pack_w_k<<<(CIN * 2 * O1 + 255) / 256, 256, 0, stream>>>(W1, Wp1, CIN, O1);
    pack_w_k<<<(O1 * 2 * O2 + 255) / 256, 256, 0, stream>>>(W2, Wp2, O1, O2);
    pack_w3t_k<<<(1024 * 256) / 256, 256, 0, stream>>>(W3, Bh3, Bl3);
    norm_w_k<<<1, 256, 0, stream>>>(pw1, pwn1, O1);
    norm_w_k<<<1, 256, 0, stream>>>(pw2, pwn2, O2);
    knn_k<<<B_G, NPG, 0, stream>>>(pos, nbr);

    // ---- level 1 ----
    gemm128_k<0><<<dim3(2 * O1 / 128, N1 / 128), 256, 0, stream>>>(
        x, Wp1, AC1, N1, 2 * O1, CIN, CIN);
    conv_agg_k<<<N1, O1, 0, stream>>>(AC1, nbr, b1, g1, be1, rm1, rv1, h1, O1);
    score_k<<<(N1 + 3) / 4, 256, 0, stream>>>(h1, pwn1, sc1, N1, O1);
    topk_rank_k<<<B_G, NPG, 0, stream>>>(sc1, NPG, KP1, gate1, perm1, o2n1);
    gather_k<<<(N2 * O1 + 255) / 256, 256, 0, stream>>>(h1, perm1, gate1, x1p, N2 * O1, 7);
    build_e2_k<<<(N2 * KNN_ + 255) / 256, 256, 0, stream>>>(nbr, perm1, o2n1, e2, N2 * KNN_);

    // ---- level 2 ----
    gemm128_k<1><<<dim3(2 * O2 / 128, N2 / 128), 256, 0, stream>>>(
        x1p, Wp2, AC2, N2, 2 * O2, O1, O1);
    conv_agg_k<<<N2, O2, 0, stream>>>(AC2, e2, b2, g2, be2, rm2, rv2, h2, O2);
    score_k<<<(N2 + 3) / 4, 256, 0, stream>>>(h2, pwn2, sc2, N2, O2);
    topk_rank_k<<<B_G, NPG, 0, stream>>>(sc2, KP1, KP2, gate2, perm2, o2n2);
    gather_bf_k<<<(N3 * O2 + 255) / 256, 256, 0, stream>>>(h2, perm2, gate2, x2h, x2l, N3 * O2);
    build_e3_k<<<(N3 * KNN_ + 255) / 256, 256, 0, stream>>>(e2, perm2, o2n2, e3, N3 * KNN_);

    // ---- level 3: split-bf16 MFMA GEMM ----
    gemm3_mfma_k<<<dim3(1024 / 128, N3 / 128), 256, 0, stream>>>(x2h, x2l, Bh3, Bl3, AC3);
    conv_agg_k<<<N3, O3, 0, stream>>>(AC3, e3, b3, g3, be3, rm3, rv3, h3, O3);

    // ---- readout ----
    gmp_k<<<B_G, O3, 0, stream>>>(h3, gmpb);
    mlpc_k<<<B_G, 512, 0, stream>>>(gmpb, Wc1, bc1, gc1, bec1, rmc1, rvc1, z1b);
    final_k<<<1, 256, 0, stream>>>(z1b, Wc2, bc2, gc2, bec2, rmc2, rvc2, out);
}

// Round 13
// 429.537 us; speedup vs baseline: 1.5861x; 1.1174x over previous
//
#include <hip/hip_runtime.h>
#include <hip/hip_bf16.h>
#include <math.h>

#define B_G  256
#define NPG  128
#define KNN_ 4
#define CIN  53
#define N1   32768
#define KP1  103
#define N2   26368   // 256*103 = 206*128
#define KP2  83
#define N3   21248   // 256*83 = 166*128
#define O1   128
#define O2   256
#define O3   512
#define EPSB 1e-5f

typedef __attribute__((ext_vector_type(8))) short bf16x8;
typedef __attribute__((ext_vector_type(4))) float f32x4;

__device__ inline ushort f2bf(float f) {          // RNE float->bf16
    unsigned u = __builtin_bit_cast(unsigned, f);
    u += 0x7fff + ((u >> 16) & 1);
    return (ushort)(u >> 16);
}
__device__ inline float bf2f(ushort h) {
    unsigned u = ((unsigned)h) << 16;
    return __builtin_bit_cast(float, u);
}

// ---------------- fused prep: norm pw1/pw2 + pack Wp1(f32) + BT2/BT3 hi/lo --
// blocks 0,1: pool-weight normalization (exact norm_w_k replication).
// blocks 2..: grid-stride packing of three weight transforms.
__global__ void prep_k(const float* __restrict__ pw1, float* __restrict__ pwn1,
                       const float* __restrict__ pw2, float* __restrict__ pwn2,
                       const float* __restrict__ W1, float* __restrict__ Wp1,
                       const float* __restrict__ W2,
                       ushort* __restrict__ Bh2, ushort* __restrict__ Bl2,
                       const float* __restrict__ W3,
                       ushort* __restrict__ Bh3, ushort* __restrict__ Bl3) {
    __shared__ float red[256];
    if (blockIdx.x < 2) {
        const float* pw = (blockIdx.x == 0) ? pw1 : pw2;
        float* pwn      = (blockIdx.x == 0) ? pwn1 : pwn2;
        int O           = (blockIdx.x == 0) ? O1 : O2;
        float s = 0.f;
        for (int c = threadIdx.x; c < O; c += 256) s += pw[c] * pw[c];
        red[threadIdx.x] = s;
        __syncthreads();
        for (int st = 128; st > 0; st >>= 1) {
            if (threadIdx.x < st) red[threadIdx.x] += red[threadIdx.x + st];
            __syncthreads();
        }
        float inv = 1.0f / sqrtf(red[0]);
        for (int c = threadIdx.x; c < O; c += 256) pwn[c] = pw[c] * inv;
        return;
    }
    const int T2 = 512 * 128;        // BT2: n in [0,512), k in [0,128)
    const int T3 = 1024 * 256;       // BT3: n in [0,1024), k in [0,256)
    const int T1 = CIN * 2 * O1;     // Wp1 f32 pack
    int total = T2 + T3 + T1;
    int stride = (gridDim.x - 2) * 256;
    for (int idx = (blockIdx.x - 2) * 256 + threadIdx.x; idx < total; idx += stride) {
        if (idx < T2) {
            int n = idx >> 7, k = idx & 127;
            float w = (n < 256) ? W2[(size_t)k * 256 + n]
                                : W2[(size_t)(128 + k) * 256 + (n - 256)];
            ushort h = f2bf(w);
            Bh2[idx] = h; Bl2[idx] = f2bf(w - bf2f(h));
        } else if (idx < T2 + T3) {
            int j = idx - T2;
            int n = j >> 8, k = j & 255;
            float w = (n < 512) ? W3[(size_t)k * 512 + n]
                                : W3[(size_t)(256 + k) * 512 + (n - 512)];
            ushort h = f2bf(w);
            Bh3[j] = h; Bl3[j] = f2bf(w - bf2f(h));
        } else {
            int j = idx - T2 - T3;
            int k = j / (2 * O1), c = j % (2 * O1);
            Wp1[j] = (c < O1) ? W1[k * O1 + c] : W1[(CIN + k) * O1 + (c - O1)];
        }
    }
}

// ---------------- KNN (k=4, per-graph; static-register top-4) -------------
__global__ void knn_k(const float* __restrict__ pos, int* __restrict__ nbr) {
    int g = blockIdx.x;
    int i = threadIdx.x;  // 128 threads
    __shared__ float px[NPG], py[NPG], pz[NPG];
    const float* p = pos + (size_t)g * NPG * 3;
    px[i] = p[i * 3 + 0]; py[i] = p[i * 3 + 1]; pz[i] = p[i * 3 + 2];
    __syncthreads();
    float b0 = 1e30f, b1 = 1e30f, b2 = 1e30f, b3 = 1e30f;
    int   i0 = 0, i1 = 0, i2 = 0, i3 = 0;
    float xi = px[i], yi = py[i], zi = pz[i];
    for (int j = 0; j < NPG; ++j) {
        float dx = xi - px[j], dy = yi - py[j], dz = zi - pz[j];
        float d2 = dx * dx + dy * dy + dz * dz;
        if (j != i && d2 < b3) {
            if (d2 < b0) {
                b3 = b2; i3 = i2; b2 = b1; i2 = i1; b1 = b0; i1 = i0; b0 = d2; i0 = j;
            } else if (d2 < b1) {
                b3 = b2; i3 = i2; b2 = b1; i2 = i1; b1 = d2; i1 = j;
            } else if (d2 < b2) {
                b3 = b2; i3 = i2; b2 = d2; i2 = j;
            } else {
                b3 = d2; i3 = j;
            }
        }
    }
    int base = (g * NPG + i) * KNN_;
    nbr[base + 0] = g * NPG + i0;
    nbr[base + 1] = g * NPG + i1;
    nbr[base + 2] = g * NPG + i2;
    nbr[base + 3] = g * NPG + i3;
}

// ---------------- fp32 tiled GEMM (level 1 only, K=53) --------------------
template <int VEC>
__global__ __launch_bounds__(256) void gemm128_k(
        const float* __restrict__ A, const float* __restrict__ Bm,
        float* __restrict__ Cm, int M, int N, int Kd, int lda) {
    __shared__ float As[16][128];
    __shared__ float Bs[16][128];
    const int tid = threadIdx.x;
    const int row0 = blockIdx.y * 128, col0 = blockIdx.x * 128;
    const int tx = tid & 15;
    const int ty = (tid >> 4) & 15;
    const int s_arow = tid >> 1, s_ak = (tid & 1) * 8;
    const int s_bk = tid >> 4, s_bc = (tid & 15) * 8;
    float acc[8][8] = {};
    for (int k0 = 0; k0 < Kd; k0 += 16) {
        if (VEC) {
            const float4* ap = (const float4*)(A + (size_t)(row0 + s_arow) * lda + k0 + s_ak);
            float4 a0 = ap[0], a1 = ap[1];
            As[s_ak + 0][s_arow] = a0.x; As[s_ak + 1][s_arow] = a0.y;
            As[s_ak + 2][s_arow] = a0.z; As[s_ak + 3][s_arow] = a0.w;
            As[s_ak + 4][s_arow] = a1.x; As[s_ak + 5][s_arow] = a1.y;
            As[s_ak + 6][s_arow] = a1.z; As[s_ak + 7][s_arow] = a1.w;
            const float4* bp = (const float4*)(Bm + (size_t)(k0 + s_bk) * N + col0 + s_bc);
            float4 b0 = bp[0], b1 = bp[1];
            *(float4*)&Bs[s_bk][s_bc] = b0;
            *(float4*)&Bs[s_bk][s_bc + 4] = b1;
        } else {
            #pragma unroll
            for (int s = 0; s < 8; ++s) {
                int kk = s_ak + s;
                As[kk][s_arow] = (k0 + kk < Kd)
                    ? A[(size_t)(row0 + s_arow) * lda + k0 + kk] : 0.f;
            }
            #pragma unroll
            for (int s = 0; s < 8; ++s) {
                Bs[s_bk][s_bc + s] = (k0 + s_bk < Kd)
                    ? Bm[(size_t)(k0 + s_bk) * N + col0 + s_bc + s] : 0.f;
            }
        }
        __syncthreads();
        #pragma unroll
        for (int kk = 0; kk < 16; ++kk) {
            float a[8], b[8];
            *(float4*)&a[0] = *(const float4*)&As[kk][ty * 4];
            *(float4*)&a[4] = *(const float4*)&As[kk][64 + ty * 4];
            *(float4*)&b[0] = *(const float4*)&Bs[kk][tx * 4];
            *(float4*)&b[4] = *(const float4*)&Bs[kk][64 + tx * 4];
            #pragma unroll
            for (int i = 0; i < 8; ++i)
                #pragma unroll
                for (int j = 0; j < 8; ++j)
                    acc[i][j] += a[i] * b[j];
        }
        __syncthreads();
    }
    #pragma unroll
    for (int i = 0; i < 8; ++i) {
        int r = row0 + ((i < 4) ? (ty * 4 + i) : (64 + ty * 4 + (i - 4)));
        size_t base = (size_t)r * N + col0;
        *(float4*)&Cm[base + tx * 4]      = *(float4*)&acc[i][0];
        *(float4*)&Cm[base + 64 + tx * 4] = *(float4*)&acc[i][4];
    }
}

// ---------------- split-bf16 MFMA GEMM (levels 2,3) -----------------------
// C[M][Nc] = A[M][Kd] @ B[Kd][Nc]; A as bf16 hi/lo planes; B transposed
// bf16 hi/lo BT[n][k].  C ~= Ah*Bh + Ah*Bl + Al*Bh.
#define LDK 40   // 32 k + 8 pad (bf16) -> 80B row stride
template <int Kd, int Nc>
__global__ __launch_bounds__(256) void gemm_mfma_k(
        const ushort* __restrict__ Ah, const ushort* __restrict__ Al,
        const ushort* __restrict__ BhT, const ushort* __restrict__ BlT,
        float* __restrict__ Cm) {
    __shared__ ushort sAh[128][LDK], sAl[128][LDK], sBh[128][LDK], sBl[128][LDK];
    const int tid = threadIdx.x;
    const int row0 = blockIdx.y * 128, col0 = blockIdx.x * 128;
    const int w = tid >> 6, lane = tid & 63;
    const int wr = (w >> 1) * 64, wc = (w & 1) * 64;
    const int fr = lane & 15, fk = (lane >> 4) * 8;
    const int s_r = tid >> 2, s_c = (tid & 3) * 8;
    f32x4 acc[4][4] = {};
    for (int k0 = 0; k0 < Kd; k0 += 32) {
        {
            size_t ga0 = (size_t)(row0 + s_r) * Kd + k0 + s_c;
            size_t ga1 = (size_t)(row0 + 64 + s_r) * Kd + k0 + s_c;
            *(uint4*)&sAh[s_r][s_c]      = *(const uint4*)&Ah[ga0];
            *(uint4*)&sAh[64 + s_r][s_c] = *(const uint4*)&Ah[ga1];
            *(uint4*)&sAl[s_r][s_c]      = *(const uint4*)&Al[ga0];
            *(uint4*)&sAl[64 + s_r][s_c] = *(const uint4*)&Al[ga1];
            size_t gb0 = (size_t)(col0 + s_r) * Kd + k0 + s_c;
            size_t gb1 = (size_t)(col0 + 64 + s_r) * Kd + k0 + s_c;
            *(uint4*)&sBh[s_r][s_c]      = *(const uint4*)&BhT[gb0];
            *(uint4*)&sBh[64 + s_r][s_c] = *(const uint4*)&BhT[gb1];
            *(uint4*)&sBl[s_r][s_c]      = *(const uint4*)&BlT[gb0];
            *(uint4*)&sBl[64 + s_r][s_c] = *(const uint4*)&BlT[gb1];
        }
        __syncthreads();
        bf16x8 fa_h[4], fa_l[4], fb_h[4], fb_l[4];
        #pragma unroll
        for (int mi = 0; mi < 4; ++mi) {
            fa_h[mi] = *(const bf16x8*)&sAh[wr + mi * 16 + fr][fk];
            fa_l[mi] = *(const bf16x8*)&sAl[wr + mi * 16 + fr][fk];
        }
        #pragma unroll
        for (int ni = 0; ni < 4; ++ni) {
            fb_h[ni] = *(const bf16x8*)&sBh[wc + ni * 16 + fr][fk];
            fb_l[ni] = *(const bf16x8*)&sBl[wc + ni * 16 + fr][fk];
        }
        #pragma unroll
        for (int mi = 0; mi < 4; ++mi)
            #pragma unroll
            for (int ni = 0; ni < 4; ++ni) {
                acc[mi][ni] = __builtin_amdgcn_mfma_f32_16x16x32_bf16(
                    fa_h[mi], fb_h[ni], acc[mi][ni], 0, 0, 0);
                acc[mi][ni] = __builtin_amdgcn_mfma_f32_16x16x32_bf16(
                    fa_h[mi], fb_l[ni], acc[mi][ni], 0, 0, 0);
                acc[mi][ni] = __builtin_amdgcn_mfma_f32_16x16x32_bf16(
                    fa_l[mi], fb_h[ni], acc[mi][ni], 0, 0, 0);
            }
        __syncthreads();
    }
    const int crow = (lane >> 4) * 4, ccol = lane & 15;
    #pragma unroll
    for (int mi = 0; mi < 4; ++mi)
        #pragma unroll
        for (int ni = 0; ni < 4; ++ni) {
            size_t base = (size_t)(row0 + wr + mi * 16 + crow) * Nc
                          + col0 + wc + ni * 16 + ccol;
            #pragma unroll
            for (int r = 0; r < 4; ++r)
                Cm[base + (size_t)r * Nc] = acc[mi][ni][r];
        }
}

// ---------------- EdgeConv aggregation ------------------------------------
__global__ void conv_agg_k(const float* __restrict__ AC, const int* __restrict__ edges,
                           const float* __restrict__ bias, const float* __restrict__ g,
                           const float* __restrict__ be, const float* __restrict__ rm,
                           const float* __restrict__ rv, float* __restrict__ out, int O) {
    int node = blockIdx.x;
    int c = threadIdx.x;            // blockDim == O
    int e0 = node * KNN_;
    int j0 = edges[e0 + 0], j1 = edges[e0 + 1], j2 = edges[e0 + 2], j3 = edges[e0 + 3];
    size_t s2O = (size_t)2 * O;
    float Ai = AC[(size_t)node * s2O + c];
    float Ci = AC[(size_t)node * s2O + O + c];
    float base = Ai - Ci + bias[c];
    float acc = 0.f; int cnt = 0;
    if (j0 >= 0) { acc += fmaxf(base + AC[(size_t)j0 * s2O + O + c], 0.f); ++cnt; }
    if (j1 >= 0) { acc += fmaxf(base + AC[(size_t)j1 * s2O + O + c], 0.f); ++cnt; }
    if (j2 >= 0) { acc += fmaxf(base + AC[(size_t)j2 * s2O + O + c], 0.f); ++cnt; }
    if (j3 >= 0) { acc += fmaxf(base + AC[(size_t)j3 * s2O + O + c], 0.f); ++cnt; }
    float h;
    if (cnt > 0) {
        float m = acc / (float)cnt;
        float sc = g[c] / sqrtf(rv[c] + EPSB);
        h = (m - rm[c]) * sc + be[c];
    } else {
        h = 0.f;
    }
    out[(size_t)node * O + c] = h;
}

// ---------------- pooling score -------------------------------------------
__global__ void score_k(const float* __restrict__ h, const float* __restrict__ pwn,
                        float* __restrict__ sc, int Nl, int O) {
    int wid = (blockIdx.x * blockDim.x + threadIdx.x) >> 6;
    int lane = threadIdx.x & 63;
    if (wid >= Nl) return;
    float s = 0.f;
    for (int c = lane; c < O; c += 64) s += h[(size_t)wid * O + c] * pwn[c];
    #pragma unroll
    for (int off = 32; off > 0; off >>= 1) s += __shfl_down(s, off);
    if (lane == 0) sc[wid] = s;
}

// ---------------- top-k (rank-based) + graph-local edge remap -------------
// rank(t) = #{j: s_j > s_t or (s_j==s_t and j<t)} == jax.lax.top_k slot.
// Edges of a graph's selected nodes reference only nodes of the same graph,
// so the remap is block-local: e_out[(g*k+u)*4+kk] = o2n[nbr_src[perm[u]*4+kk]].
__global__ void topk_edge_k(const float* __restrict__ sc, int n_l, int k_keep,
                            float* __restrict__ gate, int* __restrict__ perm,
                            const int* __restrict__ nbr_src, int* __restrict__ e_out) {
    int g = blockIdx.x;
    int t = threadIdx.x;             // 128 threads
    __shared__ float s[NPG];
    __shared__ int o2n_l[NPG], perm_l[NPG];
    if (t < n_l) s[t] = sc[(size_t)g * n_l + t];
    __syncthreads();
    if (t < n_l) {
        float v = s[t];
        int rank = 0;
        for (int j = 0; j < n_l; ++j) {
            float vj = s[j];
            rank += (vj > v || (vj == v && j < t)) ? 1 : 0;
        }
        int gi = g * n_l + t;
        if (rank < k_keep) {
            int d = g * k_keep + rank;
            perm[d] = gi;
            gate[d] = tanhf(v);
            o2n_l[t] = d;
            perm_l[rank] = gi;
        } else {
            o2n_l[t] = -1;
        }
    }
    __syncthreads();
    for (int u = t; u < k_keep; u += NPG) {
        int old = perm_l[u];                      // global old id (graph g)
        #pragma unroll
        for (int kk = 0; kk < KNN_; ++kk) {
            int srcid = nbr_src[(size_t)old * KNN_ + kk];
            int m = (srcid >= 0) ? o2n_l[srcid - g * n_l] : -1;
            e_out[((size_t)(g * k_keep + u)) * KNN_ + kk] = m;
        }
    }
}

// ---------------- gather pooled features -> bf16 hi/lo --------------------
template <int OSH>
__global__ void gather_bf_k(const float* __restrict__ h, const int* __restrict__ perm,
                            const float* __restrict__ gate,
                            ushort* __restrict__ Ah, ushort* __restrict__ Al, int total) {
    int i = blockIdx.x * blockDim.x + threadIdx.x;
    if (i >= total) return;
    int d = i >> OSH, c = i & ((1 << OSH) - 1);
    float v = h[((size_t)perm[d] << OSH) + c] * gate[d];
    ushort hh = f2bf(v);
    Ah[i] = hh;
    Al[i] = f2bf(v - bf2f(hh));
}

// ---------------- fused readout: gmp + classifier L1 + L2 + sigmoid -------
// One 512-thread block per graph; serial loop orders replicate the previous
// gmp_k / mlpc_k / final_k exactly.
__global__ void readout_k(const float* __restrict__ h3,
                          const float* __restrict__ Wc1, const float* __restrict__ bc1,
                          const float* __restrict__ gc1, const float* __restrict__ bec1,
                          const float* __restrict__ rmc1, const float* __restrict__ rvc1,
                          const float* __restrict__ Wc2, const float* __restrict__ bc2,
                          const float* __restrict__ gc2, const float* __restrict__ bec2,
                          const float* __restrict__ rmc2, const float* __restrict__ rvc2,
                          float* __restrict__ out) {
    int g = blockIdx.x, o = threadIdx.x;  // 512 threads
    __shared__ float xr[512], z1[512];
    float s = 0.f;
    for (int r = 0; r < KP2; ++r) s += h3[((size_t)(g * KP2 + r)) * O3 + o];
    xr[o] = s / (float)KP2;
    __syncthreads();
    float acc = bc1[o];
    for (int k = 0; k < 512; ++k) acc += xr[k] * Wc1[(size_t)k * 512 + o];
    acc = fmaxf(acc, 0.f);
    float sc1v = gc1[o] / sqrtf(rvc1[o] + EPSB);
    z1[o] = (acc - rmc1[o]) * sc1v + bec1[o];
    __syncthreads();
    if (o == 0) {
        float a = bc2[0];
        for (int k = 0; k < 512; ++k) a += z1[k] * Wc2[k];
        a = fmaxf(a, 0.f);
        float sc2v = gc2[0] / sqrtf(rvc2[0] + EPSB);
        float z = (a - rmc2[0]) * sc2v + bec2[0];
        out[g] = 1.f / (1.f + expf(-z));
    }
}

// ==========================================================================
extern "C" void kernel_launch(void* const* d_in, const int* in_sizes, int n_in,
                              void* d_out, int out_size, void* d_ws, size_t ws_size,
                              hipStream_t stream) {
    const float* x    = (const float*)d_in[0];
    const float* pos  = (const float*)d_in[1];
    const float* W1   = (const float*)d_in[2];
    const float* b1   = (const float*)d_in[3];
    const float* g1   = (const float*)d_in[4];
    const float* be1  = (const float*)d_in[5];
    const float* rm1  = (const float*)d_in[6];
    const float* rv1  = (const float*)d_in[7];
    const float* pw1  = (const float*)d_in[8];
    const float* W2   = (const float*)d_in[9];
    const float* b2   = (const float*)d_in[10];
    const float* g2   = (const float*)d_in[11];
    const float* be2  = (const float*)d_in[12];
    const float* rm2  = (const float*)d_in[13];
    const float* rv2  = (const float*)d_in[14];
    const float* pw2  = (const float*)d_in[15];
    const float* W3   = (const float*)d_in[16];
    const float* b3   = (const float*)d_in[17];
    const float* g3   = (const float*)d_in[18];
    const float* be3  = (const float*)d_in[19];
    const float* rm3  = (const float*)d_in[20];
    const float* rv3  = (const float*)d_in[21];
    const float* Wc1  = (const float*)d_in[22];
    const float* bc1  = (const float*)d_in[23];
    const float* gc1  = (const float*)d_in[24];
    const float* bec1 = (const float*)d_in[25];
    const float* rmc1 = (const float*)d_in[26];
    const float* rvc1 = (const float*)d_in[27];
    const float* Wc2  = (const float*)d_in[28];
    const float* bc2  = (const float*)d_in[29];
    const float* gc2  = (const float*)d_in[30];
    const float* bec2 = (const float*)d_in[31];
    const float* rmc2 = (const float*)d_in[32];
    const float* rvc2 = (const float*)d_in[33];
    float* out = (float*)d_out;

    // ---- workspace layout ----
    char* ws = (char*)d_ws;
    size_t off = 0;
    auto take = [&](size_t bytes) { size_t o = off; off = (off + bytes + 255) & ~(size_t)255; return o; };
    size_t o_nbr   = take((size_t)N1 * KNN_ * 4);
    size_t o_perm1 = take((size_t)N2 * 4);
    size_t o_perm2 = take((size_t)N3 * 4);
    size_t o_e2    = take((size_t)N2 * KNN_ * 4);
    size_t o_e3    = take((size_t)N3 * KNN_ * 4);
    size_t o_pwn1  = take((size_t)O1 * 4);
    size_t o_pwn2  = take((size_t)O2 * 4);
    size_t o_sc1   = take((size_t)N1 * 4);
    size_t o_sc2   = take((size_t)N2 * 4);
    size_t o_gate1 = take((size_t)N2 * 4);
    size_t o_gate2 = take((size_t)N3 * 4);
    size_t o_Wp1   = take((size_t)CIN * 2 * O1 * 4);
    size_t o_Bh2   = take((size_t)512 * 128 * 2);    // W2^T bf16 hi
    size_t o_Bl2   = take((size_t)512 * 128 * 2);    // W2^T bf16 lo
    size_t o_Bh3   = take((size_t)1024 * 256 * 2);   // W3^T bf16 hi
    size_t o_Bl3   = take((size_t)1024 * 256 * 2);   // W3^T bf16 lo
    size_t o_S1    = take((size_t)N3 * 2 * O3 * 4);  // max: AC3 = 87 MB
    size_t o_S2    = take((size_t)N2 * 2 * O2 * 4);  // max: AC2 = 54 MB

    int*   nbr   = (int*)(ws + o_nbr);
    int*   perm1 = (int*)(ws + o_perm1);
    int*   perm2 = (int*)(ws + o_perm2);
    int*   e2    = (int*)(ws + o_e2);
    int*   e3    = (int*)(ws + o_e3);
    float* pwn1  = (float*)(ws + o_pwn1);
    float* pwn2  = (float*)(ws + o_pwn2);
    float* sc1   = (float*)(ws + o_sc1);
    float* sc2   = (float*)(ws + o_sc2);
    float* gate1 = (float*)(ws + o_gate1);
    float* gate2 = (float*)(ws + o_gate2);
    float* Wp1   = (float*)(ws + o_Wp1);
    ushort* Bh2  = (ushort*)(ws + o_Bh2);
    ushort* Bl2  = (ushort*)(ws + o_Bl2);
    ushort* Bh3  = (ushort*)(ws + o_Bh3);
    ushort* Bl3  = (ushort*)(ws + o_Bl3);
    float* S1    = (float*)(ws + o_S1);
    float* S2    = (float*)(ws + o_S2);

    // slab aliasing (every overwrite after victim's last read):
    float* AC1 = S1;  float* h1  = S2;
    ushort* x1h = (ushort*)S1;                        // kills AC1 (last read: conv_agg1)
    ushort* x1l = x1h + (size_t)N2 * O1;
    float* AC2 = S2;                                  // kills h1 (last read: gather_bf1)
    float* h2  = S1;                                  // kills x1h/x1l (last read: gemm2)
    ushort* x2h = (ushort*)S2;                        // kills AC2 (last read: conv_agg2)
    ushort* x2l = x2h + (size_t)N3 * O2;
    float* AC3 = S1;                                  // kills h2 (last read: gather_bf2)
    float* h3  = S2;                                  // kills x2h/x2l (last read: gemm3)

    // ---- prep + knn ----
    prep_k<<<258, 256, 0, stream>>>(pw1, pwn1, pw2, pwn2, W1, Wp1,
                                    W2, Bh2, Bl2, W3, Bh3, Bl3);
    knn_k<<<B_G, NPG, 0, stream>>>(pos, nbr);

    // ---- level 1 (fp32 GEMM, K=53) ----
    gemm128_k<0><<<dim3(2 * O1 / 128, N1 / 128), 256, 0, stream>>>(
        x, Wp1, AC1, N1, 2 * O1, CIN, CIN);
    conv_agg_k<<<N1, O1, 0, stream>>>(AC1, nbr, b1, g1, be1, rm1, rv1, h1, O1);
    score_k<<<(N1 + 3) / 4, 256, 0, stream>>>(h1, pwn1, sc1, N1, O1);
    topk_edge_k<<<B_G, NPG, 0, stream>>>(sc1, NPG, KP1, gate1, perm1, nbr, e2);
    gather_bf_k<7><<<(N2 * O1 + 255) / 256, 256, 0, stream>>>(
        h1, perm1, gate1, x1h, x1l, N2 * O1);

    // ---- level 2 (split-bf16 MFMA, K=128) ----
    gemm_mfma_k<O1, 2 * O2><<<dim3(2 * O2 / 128, N2 / 128), 256, 0, stream>>>(
        x1h, x1l, Bh2, Bl2, AC2);
    conv_agg_k<<<N2, O2, 0, stream>>>(AC2, e2, b2, g2, be2, rm2, rv2, h2, O2);
    score_k<<<(N2 + 3) / 4, 256, 0, stream>>>(h2, pwn2, sc2, N2, O2);
    topk_edge_k<<<B_G, NPG, 0, stream>>>(sc2, KP1, KP2, gate2, perm2, e2, e3);
    gather_bf_k<8><<<(N3 * O2 + 255) / 256, 256, 0, stream>>>(
        h2, perm2, gate2, x2h, x2l, N3 * O2);

    // ---- level 3 (split-bf16 MFMA, K=256) ----
    gemm_mfma_k<O2, 2 * O3><<<dim3(2 * O3 / 128, N3 / 128), 256, 0, stream>>>(
        x2h, x2l, Bh3, Bl3, AC3);
    conv_agg_k<<<N3, O3, 0, stream>>>(AC3, e3, b3, g3, be3, rm3, rv3, h3, O3);

    // ---- fused readout ----
    readout_k<<<B_G, 512, 0, stream>>>(h3, Wc1, bc1, gc1, bec1, rmc1, rvc1,
                                       Wc2, bc2, gc2, bec2, rmc2, rvc2, out);
}